// Round 9
// baseline (1435.585 us; speedup 1.0000x reference)
//
#include <hip/hip_runtime.h>
#include <stdint.h>

#define NB   8
#define NPTS 4096
#define CINV 64
#define MC   1024
#define KNB  64
#define NE   (NB*MC*KNB)
#define K1   67
#define CH1  64
#define CH2  64
#define CH3  128
#define NSLOT 64
#define CAP  2048
#define NTASK (NB*MC)
#define NBLK 256      // == #CUs
#define NWORK (NBLK-NB)

typedef unsigned short u16;
typedef unsigned int   u32;
typedef unsigned long long u64;

static __device__ __forceinline__ float bf2f(u16 b){ return __uint_as_float(((u32)b)<<16); }
static __device__ __forceinline__ u16  f2bf(float f){
  u32 u = __float_as_uint(f);
  return (u16)((u + 0x7fffu + ((u>>16)&1u)) >> 16);
}
// Exact replica of reference distance: square each diff, sum as (x+y)+z, NO fma contraction.
static __device__ __forceinline__ float d2ref(float ax,float ay,float az,
                                              float bx,float by,float bz){
  float dx = ax-bx, dy = ay-by, dz = az-bz;
  return __fadd_rn(__fadd_rn(__fmul_rn(dx,dx), __fmul_rn(dy,dy)), __fmul_rn(dz,dz));
}
// ---- DPP primitives (pure VALU, no DS pipe) ----
template<int CTRL, int RMASK>
static __device__ __forceinline__ float dppmaxstep(float v){
  int t = __builtin_amdgcn_update_dpp(__float_as_int(v), __float_as_int(v),
                                      CTRL, RMASK, 0xF, false);
  return fmaxf(v, __int_as_float(t));
}
template<int CTRL, int RMASK>
static __device__ __forceinline__ float dppminstep(float v){
  int t = __builtin_amdgcn_update_dpp(__float_as_int(v), __float_as_int(v),
                                      CTRL, RMASK, 0xF, false);
  return fminf(v, __int_as_float(t));
}
template<int CTRL, int RMASK>
static __device__ __forceinline__ float dppaddstep(float v){
  // old = 0 so lanes with masked/invalid source add 0 (exact-once summation)
  int t = __builtin_amdgcn_update_dpp(0, __float_as_int(v), CTRL, RMASK, 0xF, false);
  return v + __int_as_float(t);
}
// Group-16 reductions (4 steps); EVERY lane ends with its 16-lane-group result.
static __device__ __forceinline__ float dppsum16(float v){
  v = dppaddstep<0xB1,0xF>(v); v = dppaddstep<0x4E,0xF>(v);
  v = dppaddstep<0x141,0xF>(v); v = dppaddstep<0x140,0xF>(v);
  return v;
}
static __device__ __forceinline__ float dppmax16(float v){
  v = dppmaxstep<0xB1,0xF>(v); v = dppmaxstep<0x4E,0xF>(v);
  v = dppmaxstep<0x141,0xF>(v); v = dppmaxstep<0x140,0xF>(v);
  return v;
}
static __device__ __forceinline__ float dppmin16(float v){
  v = dppminstep<0xB1,0xF>(v); v = dppminstep<0x4E,0xF>(v);
  v = dppminstep<0x141,0xF>(v); v = dppminstep<0x140,0xF>(v);
  return v;
}
// ---- f64-keyed argmax: key = bits[dist(f32) : ~idx]. Both positive doubles,
// so IEEE f64 ordering == u64 bit ordering: v_max_f64 == (max dist, lowest idx on tie).
static __device__ __forceinline__ double kpack(float d, int ni){
  return __hiloint2double(__float_as_int(d), ni);
}
template<int CTRL, int RMASK>
static __device__ __forceinline__ double dppk64(double k){
  int hi = __double2hiint(k), lo = __double2loint(k);
  int thi = __builtin_amdgcn_update_dpp(hi, hi, CTRL, RMASK, 0xF, false);
  int tlo = __builtin_amdgcn_update_dpp(lo, lo, CTRL, RMASK, 0xF, false);
  return fmax(k, __hiloint2double(thi, tlo));
}
// ---- last-block BN finalize: bit-identical to the old k_finalize kernel.
static __device__ __forceinline__ void bn_finalize(const float* __restrict__ Spart,
                                                   const float* __restrict__ g,
                                                   const float* __restrict__ bb,
                                                   const int* __restrict__ cnt_total,
                                                   float* __restrict__ Aout,
                                                   float* __restrict__ Bout,
                                                   int C, int tid) {
  if (tid < C) {
    float s = 0.f, q = 0.f;
    for (int sl = 0; sl < NSLOT; ++sl) {
      s += Spart[sl*256 + tid];
      q += Spart[sl*256 + 128 + tid];
    }
    float n = (float)(*cnt_total); if (n < 1.f) n = 1.f;
    float mu  = s / n;
    float var = q / n - mu*mu; if (var < 0.f) var = 0.f;
    float inv = 1.0f / sqrtf(var + 1e-5f);
    float a = g[tid] * inv;
    Aout[tid] = a;
    Bout[tid] = bb[tid] - mu*a;
  }
}

// ---------------------------------------------------------------- fused front kernel
struct FpsL {
  float px[NPTS], py[NPTS], pz[NPTS];
  int   sIdx[MC];
  double candD[8];   // keyed candidates, double-buffered 2x4
  float4 cbuf[16];   // centroid staging: flush 16 rows per tile to global
};
struct WkL {
  u64   keys[CAP];        // ball-query sort keys
  float Hs[64*69];        // stage-1 H tile (odd pitch)
  int   nbrS[64];
  float red[8][16][4];    // [col][s(8)+q(8)][group16]
  float cxyz[3];
  int   scnt;
  int   task;
};
union FrontL { FpsL f; WkL w; };

__global__ __launch_bounds__(512) void k_front(const float* __restrict__ x,
                                               const float* __restrict__ pos,
                                               float* __restrict__ centf,
                                               float* __restrict__ out_cent,
                                               float* __restrict__ out_bsel,
                                               const float* __restrict__ W1,
                                               float* __restrict__ Spart,
                                               u16* __restrict__ y1g,
                                               int* __restrict__ cntpc,
                                               int* __restrict__ cnt_total,
                                               int* __restrict__ progress,
                                               int* __restrict__ taskctr,
                                               int* __restrict__ done1,
                                               const float* __restrict__ g1,
                                               const float* __restrict__ b1,
                                               float* __restrict__ SC) {
  __shared__ FrontL L;
  const int tid = threadIdx.x;

  if (blockIdx.x < NB) {
    // ============ FPS producer: stage with 8 waves, then waves 4-7 EXIT.
    // 4 waves (one per SIMD), 16 pts/lane scalar scan, f64-keyed argmax.
    const int b = blockIdx.x;
    for (int i = tid; i < NPTS; i += 512) {
      size_t o = ((size_t)b*NPTS + i)*3;
      L.f.px[i] = pos[o]; L.f.py[i] = pos[o+1]; L.f.pz[i] = pos[o+2];
    }
    __syncthreads();          // 8-wave barrier (staging)
    if (tid >= 256) return;   // narrow the workgroup: barriers below sync 4 waves

    float cxr[16], cyr[16], czr[16], dist[16];
    int nio[16];
    #pragma unroll
    for (int j = 0; j < 16; ++j) {
      int p = tid*16 + j;
      cxr[j] = L.f.px[p]; cyr[j] = L.f.py[p]; czr[j] = L.f.pz[p];
      dist[j] = 1e10f;
      nio[j] = ~p;
    }
    const int lane = tid & 63, w = tid >> 6;   // w in 0..3
    float qx = L.f.px[0], qy = L.f.py[0], qz = L.f.pz[0];
    if (tid == 0) {
      L.f.sIdx[0] = 0;
      L.f.cbuf[0] = make_float4(qx, qy, qz, 0.f);
    }

    for (int it = 1; it < MC; ++it) {
      // ---- scan: pure min, no compares, no vcc
      #pragma unroll
      for (int j = 0; j < 16; ++j) {
        float d = d2ref(cxr[j], cyr[j], czr[j], qx, qy, qz);
        dist[j] = fminf(dist[j], d);
      }
      // ---- keyed pairwise tree over 16 points (15 x v_max_f64)
      double t0 = fmax(kpack(dist[0],  nio[0]),  kpack(dist[1],  nio[1]));
      double t1 = fmax(kpack(dist[2],  nio[2]),  kpack(dist[3],  nio[3]));
      double t2 = fmax(kpack(dist[4],  nio[4]),  kpack(dist[5],  nio[5]));
      double t3 = fmax(kpack(dist[6],  nio[6]),  kpack(dist[7],  nio[7]));
      double t4 = fmax(kpack(dist[8],  nio[8]),  kpack(dist[9],  nio[9]));
      double t5 = fmax(kpack(dist[10], nio[10]), kpack(dist[11], nio[11]));
      double t6 = fmax(kpack(dist[12], nio[12]), kpack(dist[13], nio[13]));
      double t7 = fmax(kpack(dist[14], nio[14]), kpack(dist[15], nio[15]));
      double u0 = fmax(t0, t1), u1 = fmax(t2, t3), u2 = fmax(t4, t5), u3 = fmax(t6, t7);
      double bk = fmax(fmax(u0, u1), fmax(u2, u3));
      // ---- wave keyed reduce (6 DPP steps), winner key valid in lane 63
      bk = dppk64<0xB1,0xF>(bk);
      bk = dppk64<0x4E,0xF>(bk);
      bk = dppk64<0x141,0xF>(bk);
      bk = dppk64<0x140,0xF>(bk);
      bk = dppk64<0x142,0xA>(bk);
      bk = dppk64<0x143,0xC>(bk);
      if (lane == 63) L.f.candD[(it & 1)*4 + w] = bk;
      __syncthreads();   // 4-wave barrier
      // ---- resolve 4 candidates branch-free (2 keyed DPP steps, all lanes uniform)
      double ck = L.f.candD[(it & 1)*4 + (lane & 3)];
      ck = dppk64<0xB1,0xF>(ck);
      ck = dppk64<0x4E,0xF>(ck);
      int wi = (int)(~(u32)__double2loint(ck));   // winning point index (uniform)
      qx = L.f.px[wi]; qy = L.f.py[wi]; qz = L.f.pz[wi];   // broadcast LDS reads
      // flush PREVIOUS 16-row tile then release-publish progress
      if ((it & 15) == 0 && tid < 16) {
        int mrow = it - 16 + tid;
        float4 cc = L.f.cbuf[tid];
        int r = b*MC + mrow;
        centf[r*3+0] = cc.x; centf[r*3+1] = cc.y; centf[r*3+2] = cc.z;
        if (tid == 0)
          __hip_atomic_store(progress + b, it, __ATOMIC_RELEASE, __HIP_MEMORY_SCOPE_AGENT);
      }
      if (tid == 0) {
        L.f.sIdx[it] = wi;
        L.f.cbuf[it & 15] = make_float4(qx, qy, qz, 0.f);
      }
    }
    __syncthreads();   // 4-wave barrier
    // final tile flush (rows MC-16..MC-1) + progress = MC
    if (tid < 16) {
      int mrow = MC - 16 + tid;
      float4 cc = L.f.cbuf[tid];
      int r = b*MC + mrow;
      centf[r*3+0] = cc.x; centf[r*3+1] = cc.y; centf[r*3+2] = cc.z;
      if (tid == 0)
        __hip_atomic_store(progress + b, MC, __ATOMIC_RELEASE, __HIP_MEMORY_SCOPE_AGENT);
    }
    // epilogue: out_cent / out_bsel from sIdx (off the critical path; 256 threads)
    for (int m2_ = tid; m2_ < MC; m2_ += 256) {
      int i = L.f.sIdx[m2_];
      int r = b*MC + m2_;
      out_cent[r*3+0] = L.f.px[i]; out_cent[r*3+1] = L.f.py[i]; out_cent[r*3+2] = L.f.pz[i];
      out_bsel[r] = (float)b;
    }
    return;
  }

  // ============ persistent workers: ball query + stage-1 per centroid (512 thr)
  for (;;) {
    if (tid == 0) {
      int t = atomicAdd(taskctr, 1);
      L.w.task = t;
      if (t < NTASK) {
        int m = t >> 3, b = t & 7;
        while (__hip_atomic_load(progress + b, __ATOMIC_ACQUIRE, __HIP_MEMORY_SCOPE_AGENT) < m + 1)
          __builtin_amdgcn_s_sleep(8);
        int bm = b*MC + m;
        L.w.cxyz[0] = __hip_atomic_load(centf + bm*3 + 0, __ATOMIC_RELAXED, __HIP_MEMORY_SCOPE_AGENT);
        L.w.cxyz[1] = __hip_atomic_load(centf + bm*3 + 1, __ATOMIC_RELAXED, __HIP_MEMORY_SCOPE_AGENT);
        L.w.cxyz[2] = __hip_atomic_load(centf + bm*3 + 2, __ATOMIC_RELAXED, __HIP_MEMORY_SCOPE_AGENT);
      }
      L.w.scnt = 0;
    }
    __syncthreads();
    const int t = L.w.task;
    if (t >= NTASK) {
      // -------- last worker block fuses BN1 finalize (replaces k_finalize #1)
      if (tid == 0) {
        int d = __hip_atomic_fetch_add(done1, 1, __ATOMIC_ACQ_REL, __HIP_MEMORY_SCOPE_AGENT);
        L.w.scnt = (d == NWORK - 1) ? 1 : 0;
      }
      __syncthreads();
      if (L.w.scnt)
        bn_finalize(Spart, g1, b1, cnt_total, SC + 0, SC + 64, CH1, tid);
      return;
    }
    const int m = t >> 3, b = t & 7, bm = b*MC + m;
    const float cx = L.w.cxyz[0], cy = L.w.cxyz[1], cz = L.w.cxyz[2];

    // ---- ball query (exact ref semantics)
    for (int i = tid; i < NPTS; i += 512) {
      size_t o = ((size_t)b*NPTS + i)*3;
      float d = d2ref(cx, cy, cz, pos[o], pos[o+1], pos[o+2]);
      if (d <= 0.04f) {
        int p = atomicAdd(&L.w.scnt, 1);
        if (p < CAP) L.w.keys[p] = ((u64)__float_as_uint(d) << 32) | (u32)i;
      }
    }
    __syncthreads();
    int n = L.w.scnt; if (n > CAP) n = CAP;
    int P = 64; while (P < n) P <<= 1;
    for (int i = n + tid; i < P; i += 512) L.w.keys[i] = ~0ull;
    __syncthreads();
    for (int ks = 2; ks <= P; ks <<= 1)
      for (int js = ks >> 1; js > 0; js >>= 1) {
        for (int i = tid; i < P; i += 512) {
          int l = i ^ js;
          if (l > i) {
            u64 a = L.w.keys[i], c = L.w.keys[l];
            bool up = ((i & ks) == 0);
            if ((a > c) == up) { L.w.keys[i] = c; L.w.keys[l] = a; }
          }
        }
        __syncthreads();
      }
    const int c = n < KNB ? n : KNB;
    if (tid < KNB) L.w.nbrS[tid] = (tid < c) ? (int)(u32)(L.w.keys[tid] & 0xffffffffu) : 0;
    if (tid == 0) { cntpc[bm] = c; atomicAdd(cnt_total, c); }
    __syncthreads();

    // ---- stage-1: H = [x_j, p_j - c_i] (64x67) staged in LDS
    {
      const int ge = tid >> 3, qb = tid & 7;
      const float4* xr = (const float4*)(x + ((size_t)(b*NPTS + L.w.nbrS[ge]))*CINV);
      #pragma unroll
      for (int rep = 0; rep < 2; ++rep) {
        int q = qb + rep*8;
        float4 v = xr[q];
        float* d = L.w.Hs + ge*69 + q*4;
        d[0] = v.x; d[1] = v.y; d[2] = v.z; d[3] = v.w;
      }
    }
    if (tid < 64) {
      int row = b*NPTS + L.w.nbrS[tid];
      L.w.Hs[tid*69+64] = pos[(size_t)row*3+0] - cx;
      L.w.Hs[tid*69+65] = pos[(size_t)row*3+1] - cy;
      L.w.Hs[tid*69+66] = pos[(size_t)row*3+2] - cz;
    }
    __syncthreads();

    // ---- GEMM: thread = (edge, col of 8 ch); W via wave-uniform SCALAR loads
    const int edge = tid & 63;
    const int col  = __builtin_amdgcn_readfirstlane(tid >> 6);  // 0..7
    float acc[8];
    #pragma unroll
    for (int j = 0; j < 8; ++j) acc[j] = 0.f;
    const float* hrow = L.w.Hs + edge*69;
    const float* wcol = W1 + col*8;
    for (int k = 0; k < K1; ++k) {
      float hk = hrow[k];
      const float4* w4 = (const float4*)(wcol + k*CH1);
      float4 a = w4[0], bq = w4[1];
      acc[0] = fmaf(hk, a.x,  acc[0]); acc[1] = fmaf(hk, a.y,  acc[1]);
      acc[2] = fmaf(hk, a.z,  acc[2]); acc[3] = fmaf(hk, a.w,  acc[3]);
      acc[4] = fmaf(hk, bq.x, acc[4]); acc[5] = fmaf(hk, bq.y, acc[5]);
      acc[6] = fmaf(hk, bq.z, acc[6]); acc[7] = fmaf(hk, bq.w, acc[7]);
    }
    const bool valid = edge < c;
    #pragma unroll
    for (int j = 0; j < 8; ++j) acc[j] = valid ? acc[j] : 0.f;
    u32* dst = (u32*)(y1g + ((size_t)bm*64 + edge)*CH1 + col*8);
    #pragma unroll
    for (int j = 0; j < 4; ++j)
      dst[j] = (u32)f2bf(acc[2*j]) | ((u32)f2bf(acc[2*j+1]) << 16);
    // group-16 DPP reductions (pure VALU), 4 partials per value
    #pragma unroll
    for (int j = 0; j < 8; ++j) {
      float s = dppsum16(acc[j]);
      float q = dppsum16(acc[j]*acc[j]);
      if ((edge & 15) == 0) {
        L.w.red[col][j][edge>>4]   = s;
        L.w.red[col][8+j][edge>>4] = q;
      }
    }
    __syncthreads();
    const int slot = bm & (NSLOT-1);
    if (tid < 64) {
      float4 g = *(const float4*)&L.w.red[tid>>3][tid&7][0];
      atomicAdd(&Spart[slot*256 + tid], (g.x+g.y)+(g.z+g.w));
    } else if (tid < 128) {
      int cc = tid - 64;
      float4 g = *(const float4*)&L.w.red[cc>>3][8+(cc&7)][0];
      atomicAdd(&Spart[slot*256 + 128 + cc], (g.x+g.y)+(g.z+g.w));
    }
    // top-of-loop __syncthreads() isolates this task's LDS reads from next task's writes
  }
}

// ---------------------------------------------------------------- stage 2: relu(bn1(y1)) @ W2
__global__ __launch_bounds__(256) void k_s2(const u16* __restrict__ y1g,
                                            const float* __restrict__ SC,
                                            const float* __restrict__ W2,
                                            const int* __restrict__ cntpc,
                                            float* __restrict__ Spart,
                                            u16* __restrict__ y2g,
                                            int* __restrict__ done2,
                                            const float* __restrict__ g2,
                                            const float* __restrict__ b2,
                                            const int* __restrict__ cnt_total,
                                            float* __restrict__ SCout) {
  __shared__ float Hs[64*65];
  __shared__ float ABs[128];
  __shared__ float red[4][32][4];
  __shared__ int   cntS;
  __shared__ int   lastS;
  const int tid = threadIdx.x, bm = blockIdx.x;
  if (tid == 0) cntS = cntpc[bm];
  if (tid < 128) ABs[tid] = SC[tid];            // A1(64) B1(64)
  __syncthreads();
  {
    const u32* yt = (const u32*)y1g + (size_t)bm*2048;  // 64 edges * 32 u32
    #pragma unroll
    for (int rep = 0; rep < 8; ++rep) {
      int g = rep*256 + tid;
      int e = g >> 5, c2 = g & 31, ch = c2*2;
      u32 v = yt[g];
      float lo = fmaxf(fmaf(bf2f((u16)(v & 0xffff)), ABs[ch],   ABs[64+ch]),   0.f);
      float hi = fmaxf(fmaf(bf2f((u16)(v >> 16)),    ABs[ch+1], ABs[64+ch+1]), 0.f);
      Hs[e*65 + ch] = lo; Hs[e*65 + ch + 1] = hi;
    }
  }
  __syncthreads();

  const int edge = tid & 63;
  const int col  = __builtin_amdgcn_readfirstlane(tid >> 6);
  float acc[16];
  #pragma unroll
  for (int j = 0; j < 16; ++j) acc[j] = 0.f;
  const float* hrow = Hs + edge*65;
  const float* wcol = W2 + col*16;
  for (int k = 0; k < CH1; ++k) {
    float hk = hrow[k];
    const float4* w4 = (const float4*)(wcol + k*CH2);
    #pragma unroll
    for (int q = 0; q < 4; ++q) {
      float4 wv = w4[q];
      acc[q*4+0] = fmaf(hk, wv.x, acc[q*4+0]);
      acc[q*4+1] = fmaf(hk, wv.y, acc[q*4+1]);
      acc[q*4+2] = fmaf(hk, wv.z, acc[q*4+2]);
      acc[q*4+3] = fmaf(hk, wv.w, acc[q*4+3]);
    }
  }
  const bool valid = edge < cntS;
  #pragma unroll
  for (int j = 0; j < 16; ++j) acc[j] = valid ? acc[j] : 0.f;
  u32* dst = (u32*)(y2g + ((size_t)bm*64 + edge)*CH2 + col*16);
  #pragma unroll
  for (int j = 0; j < 8; ++j)
    dst[j] = (u32)f2bf(acc[2*j]) | ((u32)f2bf(acc[2*j+1]) << 16);
  #pragma unroll
  for (int j = 0; j < 16; ++j) {
    float s = dppsum16(acc[j]);
    float q = dppsum16(acc[j]*acc[j]);
    if ((edge & 15) == 0) {
      red[col][j][edge>>4]    = s;
      red[col][16+j][edge>>4] = q;
    }
  }
  __syncthreads();
  const int slot = bm & (NSLOT-1);
  if (tid < 64) {
    float4 g = *(const float4*)&red[tid>>4][tid&15][0];
    atomicAdd(&Spart[slot*256 + tid], (g.x+g.y)+(g.z+g.w));
  } else if (tid < 128) {
    int c = tid - 64;
    float4 g = *(const float4*)&red[c>>4][16+(c&15)][0];
    atomicAdd(&Spart[slot*256 + 128 + c], (g.x+g.y)+(g.z+g.w));
  }
  // -------- last block fuses BN2 finalize (replaces k_finalize #2)
  __syncthreads();   // drain this block's Spart atomics
  if (tid == 0) {
    int d = __hip_atomic_fetch_add(done2, 1, __ATOMIC_ACQ_REL, __HIP_MEMORY_SCOPE_AGENT);
    lastS = (d == NTASK - 1) ? 1 : 0;
  }
  __syncthreads();
  if (lastS)
    bn_finalize(Spart, g2, b2, cnt_total, SCout + 0, SCout + 64, CH2, tid);
}

// ---------------------------------------------------------------- stage 3: relu(bn2(y2)) @ W3, + per-(bm,ch) max/min of f32 y3
__global__ __launch_bounds__(256) void k_s3(const u16* __restrict__ y2g,
                                            const float* __restrict__ SC,
                                            const float* __restrict__ W3,
                                            const int* __restrict__ cntpc,
                                            float* __restrict__ Spart,
                                            float* __restrict__ mxmn,
                                            int* __restrict__ done3,
                                            const float* __restrict__ g3,
                                            const float* __restrict__ b3,
                                            const int* __restrict__ cnt_total,
                                            float* __restrict__ SCout) {
  __shared__ float Hs[64*65];
  __shared__ float ABs[128];
  __shared__ float red[4][64][4];
  __shared__ float redm[4][64][4];
  __shared__ int   cntS;
  __shared__ int   lastS;
  const int tid = threadIdx.x, bm = blockIdx.x;
  if (tid == 0) cntS = cntpc[bm];
  if (tid < 128) ABs[tid] = SC[128 + tid];      // A2(64) B2(64)
  __syncthreads();
  {
    const u32* yt = (const u32*)y2g + (size_t)bm*2048;
    #pragma unroll
    for (int rep = 0; rep < 8; ++rep) {
      int g = rep*256 + tid;
      int e = g >> 5, c2 = g & 31, ch = c2*2;
      u32 v = yt[g];
      float lo = fmaxf(fmaf(bf2f((u16)(v & 0xffff)), ABs[ch],   ABs[64+ch]),   0.f);
      float hi = fmaxf(fmaf(bf2f((u16)(v >> 16)),    ABs[ch+1], ABs[64+ch+1]), 0.f);
      Hs[e*65 + ch] = lo; Hs[e*65 + ch + 1] = hi;
    }
  }
  __syncthreads();

  const int edge = tid & 63;
  const int col  = __builtin_amdgcn_readfirstlane(tid >> 6);  // owns 32 of 128 ch
  float acc[32];
  #pragma unroll
  for (int j = 0; j < 32; ++j) acc[j] = 0.f;
  const float* hrow = Hs + edge*65;
  const float* wcol = W3 + col*32;
  for (int k = 0; k < CH2; ++k) {
    float hk = hrow[k];
    const float4* w4 = (const float4*)(wcol + k*CH3);
    #pragma unroll
    for (int q = 0; q < 8; ++q) {
      float4 wv = w4[q];
      acc[q*4+0] = fmaf(hk, wv.x, acc[q*4+0]);
      acc[q*4+1] = fmaf(hk, wv.y, acc[q*4+1]);
      acc[q*4+2] = fmaf(hk, wv.z, acc[q*4+2]);
      acc[q*4+3] = fmaf(hk, wv.w, acc[q*4+3]);
    }
  }
  const bool valid = edge < cntS;
  #pragma unroll
  for (int j = 0; j < 32; ++j) {
    float mxv = valid ? acc[j] : -1e30f;
    float mnv = valid ? acc[j] :  1e30f;
    float av  = valid ? acc[j] : 0.f;
    float s  = dppsum16(av);
    float q  = dppsum16(av*av);
    float mx = dppmax16(mxv);
    float mn = dppmin16(mnv);
    if ((edge & 15) == 0) {
      red[col][j][edge>>4]     = s;
      red[col][32+j][edge>>4]  = q;
      redm[col][j][edge>>4]    = mx;
      redm[col][32+j][edge>>4] = mn;
    }
  }
  __syncthreads();
  const int slot = bm & (NSLOT-1);
  if (tid < 128) {
    float4 g = *(const float4*)&red[tid>>5][tid&31][0];
    atomicAdd(&Spart[slot*256 + tid], (g.x+g.y)+(g.z+g.w));
    float4 gm = *(const float4*)&redm[tid>>5][tid&31][0];
    mxmn[(size_t)bm*256 + tid] = fmaxf(fmaxf(gm.x, gm.y), fmaxf(gm.z, gm.w));
  } else {
    int c = tid - 128;
    float4 g = *(const float4*)&red[c>>5][32+(c&31)][0];
    atomicAdd(&Spart[slot*256 + 128 + c], (g.x+g.y)+(g.z+g.w));
    float4 gm = *(const float4*)&redm[c>>5][32+(c&31)][0];
    mxmn[(size_t)bm*256 + 128 + c] = fminf(fminf(gm.x, gm.y), fminf(gm.z, gm.w));
  }
  // -------- last block fuses BN3 finalize (replaces k_finalize #3)
  __syncthreads();   // drain this block's Spart atomics
  if (tid == 0) {
    int d = __hip_atomic_fetch_add(done3, 1, __ATOMIC_ACQ_REL, __HIP_MEMORY_SCOPE_AGENT);
    lastS = (d == NTASK - 1) ? 1 : 0;
  }
  __syncthreads();
  if (lastS)
    bn_finalize(Spart, g3, b3, cnt_total, SCout + 0, SCout + 128, CH3, tid);
}

// ---------------------------------------------------------------- stage 4: bn3+relu+maxpool from per-block max/min
// max_e relu(a*y+b) = relu(a*max_e(y)+b) for a>0 (monotone correctly-rounded ops
// commute with max); use min_e(y) for a<0. Exact vs the elementwise scan.
__global__ __launch_bounds__(128) void k_s4(const float* __restrict__ mxmn,
                                            const float* __restrict__ SC,
                                            float* __restrict__ out0) {
  const int tid = threadIdx.x, bm = blockIdx.x;
  const float a = SC[256 + tid], b = SC[384 + tid];
  const float mx = mxmn[(size_t)bm*256 + tid];
  const float mn = mxmn[(size_t)bm*256 + 128 + tid];
  const float v = (a > 0.f) ? mx : mn;
  out0[(size_t)bm*CH3 + tid] = fmaxf(fmaf(v, a, b), 0.f);
}

// ---------------------------------------------------------------- host
extern "C" void kernel_launch(void* const* d_in, const int* in_sizes, int n_in,
                              void* d_out, int out_size, void* d_ws, size_t ws_size,
                              hipStream_t stream) {
  (void)in_sizes; (void)n_in; (void)out_size; (void)ws_size;
  const float* x   = (const float*)d_in[0];
  const float* pos = (const float*)d_in[1];
  const float* W1  = (const float*)d_in[3];
  const float* g1  = (const float*)d_in[4];
  const float* b1  = (const float*)d_in[5];
  const float* W2  = (const float*)d_in[6];
  const float* g2  = (const float*)d_in[7];
  const float* b2  = (const float*)d_in[8];
  const float* W3  = (const float*)d_in[9];
  const float* g3  = (const float*)d_in[10];
  const float* b3  = (const float*)d_in[11];

  float* out0     = (float*)d_out;
  float* out_cent = out0 + (size_t)NB*MC*CH3;
  float* out_bsel = out_cent + (size_t)NB*MC*3;

  char* base = (char*)d_ws;
  size_t off = 0;
  auto carve = [&](size_t bytes) -> char* {
    char* p = base + off;
    off = (off + bytes + 255) & ~(size_t)255;
    return p;
  };
  float* centf = (float*)carve(sizeof(float)*NB*MC*3);
  int*   cntpc = (int*)  carve(sizeof(int)*NB*MC);
  char*  zeroblk = carve(256 + 3*NSLOT*256*sizeof(float));
  int*   cnt_total = (int*)zeroblk;
  int*   taskctr   = cnt_total + 1;
  int*   progress  = cnt_total + 2;    // 8 ints
  int*   done1     = cnt_total + 10;
  int*   done2     = cnt_total + 11;
  int*   done3     = cnt_total + 12;
  float* Sp1 = (float*)(zeroblk + 256);
  float* Sp2 = Sp1 + NSLOT*256;
  float* Sp3 = Sp2 + NSLOT*256;
  float* SC = (float*)carve(512*sizeof(float));  // A1 B1 A2 B2 A3(128) B3(128)
  u16* y1g = (u16*)carve((size_t)NE*CH1*2);
  u16* y2g = (u16*)carve((size_t)NE*CH2*2);
  float* mxmn = (float*)carve((size_t)NB*MC*256*sizeof(float));  // 8 MB: max(128) min(128) per bm

  hipMemsetAsync(zeroblk, 0, 256 + 3*NSLOT*256*sizeof(float), stream);
  k_front<<<NBLK, 512, 0, stream>>>(x, pos, centf, out_cent, out_bsel,
                                    W1, Sp1, y1g, cntpc, cnt_total, progress, taskctr,
                                    done1, g1, b1, SC);
  dim3 sg(NB*MC), sb(256);
  k_s2<<<sg, sb, 0, stream>>>(y1g, SC, W2, cntpc, Sp2, y2g,
                              done2, g2, b2, cnt_total, SC + 128);
  k_s3<<<sg, sb, 0, stream>>>(y2g, SC, W3, cntpc, Sp3, mxmn,
                              done3, g3, b3, cnt_total, SC + 256);
  k_s4<<<sg, 128, 0, stream>>>(mxmn, SC, out0);
}

// Round 10
// 1037.961 us; speedup vs baseline: 1.3831x; 1.3831x over previous
//
#include <hip/hip_runtime.h>
#include <stdint.h>

#define NB   8
#define NPTS 4096
#define CINV 64
#define MC   1024
#define KNB  64
#define NE   (NB*MC*KNB)
#define K1   67
#define CH1  64
#define CH2  64
#define CH3  128
#define NSLOT 64
#define CAP  2048
#define NTASK (NB*MC)
#define NBLK 256      // == #CUs

typedef unsigned short u16;
typedef unsigned int   u32;
typedef unsigned long long u64;

static __device__ __forceinline__ float bf2f(u16 b){ return __uint_as_float(((u32)b)<<16); }
static __device__ __forceinline__ u16  f2bf(float f){
  u32 u = __float_as_uint(f);
  return (u16)((u + 0x7fffu + ((u>>16)&1u)) >> 16);
}
// Exact replica of reference distance: square each diff, sum as (x+y)+z, NO fma contraction.
static __device__ __forceinline__ float d2ref(float ax,float ay,float az,
                                              float bx,float by,float bz){
  float dx = ax-bx, dy = ay-by, dz = az-bz;
  return __fadd_rn(__fadd_rn(__fmul_rn(dx,dx), __fmul_rn(dy,dy)), __fmul_rn(dz,dz));
}
// ---- DPP primitives (pure VALU, no DS pipe) ----
template<int CTRL, int RMASK>
static __device__ __forceinline__ float dppmaxstep(float v){
  int t = __builtin_amdgcn_update_dpp(__float_as_int(v), __float_as_int(v),
                                      CTRL, RMASK, 0xF, false);
  return fmaxf(v, __int_as_float(t));
}
template<int CTRL, int RMASK>
static __device__ __forceinline__ float dppminstep(float v){
  int t = __builtin_amdgcn_update_dpp(__float_as_int(v), __float_as_int(v),
                                      CTRL, RMASK, 0xF, false);
  return fminf(v, __int_as_float(t));
}
template<int CTRL, int RMASK>
static __device__ __forceinline__ float dppaddstep(float v){
  // old = 0 so lanes with masked/invalid source add 0 (exact-once summation)
  int t = __builtin_amdgcn_update_dpp(0, __float_as_int(v), CTRL, RMASK, 0xF, false);
  return v + __int_as_float(t);
}
// Group-16 reductions (4 steps); EVERY lane ends with its 16-lane-group result.
static __device__ __forceinline__ float dppsum16(float v){
  v = dppaddstep<0xB1,0xF>(v); v = dppaddstep<0x4E,0xF>(v);
  v = dppaddstep<0x141,0xF>(v); v = dppaddstep<0x140,0xF>(v);
  return v;
}
static __device__ __forceinline__ float dppmax16(float v){
  v = dppmaxstep<0xB1,0xF>(v); v = dppmaxstep<0x4E,0xF>(v);
  v = dppmaxstep<0x141,0xF>(v); v = dppmaxstep<0x140,0xF>(v);
  return v;
}
static __device__ __forceinline__ float dppmin16(float v){
  v = dppminstep<0xB1,0xF>(v); v = dppminstep<0x4E,0xF>(v);
  v = dppminstep<0x141,0xF>(v); v = dppminstep<0x140,0xF>(v);
  return v;
}
// ---- f64-keyed argmax: key = bits[dist(f32) : ~idx]. Both positive doubles,
// so IEEE f64 ordering == u64 bit ordering: v_max_f64 == (max dist, lowest idx on tie).
static __device__ __forceinline__ double kpack(float d, int ni){
  return __hiloint2double(__float_as_int(d), ni);
}
template<int CTRL, int RMASK>
static __device__ __forceinline__ double dppk64(double k){
  int hi = __double2hiint(k), lo = __double2loint(k);
  int thi = __builtin_amdgcn_update_dpp(hi, hi, CTRL, RMASK, 0xF, false);
  int tlo = __builtin_amdgcn_update_dpp(lo, lo, CTRL, RMASK, 0xF, false);
  return fmax(k, __hiloint2double(thi, tlo));
}

// ---------------------------------------------------------------- fused front kernel
struct FpsL {
  float px[NPTS], py[NPTS], pz[NPTS];
  int   sIdx[MC];
  double candD[8];   // keyed candidates, double-buffered 2x4
  float4 cbuf[16];   // centroid staging: flush 16 rows per tile to global
};
struct WkL {
  u64   keys[CAP];        // ball-query sort keys
  float Hs[64*69];        // stage-1 H tile (odd pitch)
  int   nbrS[64];
  float red[8][16][4];    // [col][s(8)+q(8)][group16]
  float cxyz[3];
  int   scnt;
  int   task;
};
union FrontL { FpsL f; WkL w; };

__global__ __launch_bounds__(512) void k_front(const float* __restrict__ x,
                                               const float* __restrict__ pos,
                                               float* __restrict__ centf,
                                               float* __restrict__ out_cent,
                                               float* __restrict__ out_bsel,
                                               const float* __restrict__ W1,
                                               float* __restrict__ Spart,
                                               u16* __restrict__ y1g,
                                               int* __restrict__ cntpc,
                                               int* __restrict__ cnt_total,
                                               int* __restrict__ progress,
                                               int* __restrict__ taskctr) {
  __shared__ FrontL L;
  const int tid = threadIdx.x;

  if (blockIdx.x < NB) {
    // ============ FPS producer: stage with 8 waves, then waves 4-7 EXIT.
    // 4 waves (one per SIMD), 16 pts/lane scalar scan, f64-keyed argmax.
    const int b = blockIdx.x;
    for (int i = tid; i < NPTS; i += 512) {
      size_t o = ((size_t)b*NPTS + i)*3;
      L.f.px[i] = pos[o]; L.f.py[i] = pos[o+1]; L.f.pz[i] = pos[o+2];
    }
    __syncthreads();          // 8-wave barrier (staging)
    if (tid >= 256) return;   // narrow the workgroup: barriers below sync 4 waves

    float cxr[16], cyr[16], czr[16], dist[16];
    int nio[16];
    #pragma unroll
    for (int j = 0; j < 16; ++j) {
      int p = tid*16 + j;
      cxr[j] = L.f.px[p]; cyr[j] = L.f.py[p]; czr[j] = L.f.pz[p];
      dist[j] = 1e10f;
      nio[j] = ~p;
    }
    const int lane = tid & 63, w = tid >> 6;   // w in 0..3
    float qx = L.f.px[0], qy = L.f.py[0], qz = L.f.pz[0];
    if (tid == 0) {
      L.f.sIdx[0] = 0;
      L.f.cbuf[0] = make_float4(qx, qy, qz, 0.f);
    }

    for (int it = 1; it < MC; ++it) {
      // ---- scan: pure min, no compares, no vcc
      #pragma unroll
      for (int j = 0; j < 16; ++j) {
        float d = d2ref(cxr[j], cyr[j], czr[j], qx, qy, qz);
        dist[j] = fminf(dist[j], d);
      }
      // ---- keyed pairwise tree over 16 points (15 x v_max_f64)
      double t0 = fmax(kpack(dist[0],  nio[0]),  kpack(dist[1],  nio[1]));
      double t1 = fmax(kpack(dist[2],  nio[2]),  kpack(dist[3],  nio[3]));
      double t2 = fmax(kpack(dist[4],  nio[4]),  kpack(dist[5],  nio[5]));
      double t3 = fmax(kpack(dist[6],  nio[6]),  kpack(dist[7],  nio[7]));
      double t4 = fmax(kpack(dist[8],  nio[8]),  kpack(dist[9],  nio[9]));
      double t5 = fmax(kpack(dist[10], nio[10]), kpack(dist[11], nio[11]));
      double t6 = fmax(kpack(dist[12], nio[12]), kpack(dist[13], nio[13]));
      double t7 = fmax(kpack(dist[14], nio[14]), kpack(dist[15], nio[15]));
      double u0 = fmax(t0, t1), u1 = fmax(t2, t3), u2 = fmax(t4, t5), u3 = fmax(t6, t7);
      double bk = fmax(fmax(u0, u1), fmax(u2, u3));
      // ---- wave keyed reduce (6 DPP steps), winner key valid in lane 63
      bk = dppk64<0xB1,0xF>(bk);
      bk = dppk64<0x4E,0xF>(bk);
      bk = dppk64<0x141,0xF>(bk);
      bk = dppk64<0x140,0xF>(bk);
      bk = dppk64<0x142,0xA>(bk);
      bk = dppk64<0x143,0xC>(bk);
      if (lane == 63) L.f.candD[(it & 1)*4 + w] = bk;
      __syncthreads();   // 4-wave barrier
      // ---- resolve 4 candidates branch-free (2 keyed DPP steps, all lanes uniform)
      double ck = L.f.candD[(it & 1)*4 + (lane & 3)];
      ck = dppk64<0xB1,0xF>(ck);
      ck = dppk64<0x4E,0xF>(ck);
      int wi = (int)(~(u32)__double2loint(ck));   // winning point index (uniform)
      qx = L.f.px[wi]; qy = L.f.py[wi]; qz = L.f.pz[wi];   // broadcast LDS reads
      // flush PREVIOUS 16-row tile then release-publish progress
      if ((it & 15) == 0 && tid < 16) {
        int mrow = it - 16 + tid;
        float4 cc = L.f.cbuf[tid];
        int r = b*MC + mrow;
        centf[r*3+0] = cc.x; centf[r*3+1] = cc.y; centf[r*3+2] = cc.z;
        if (tid == 0)
          __hip_atomic_store(progress + b, it, __ATOMIC_RELEASE, __HIP_MEMORY_SCOPE_AGENT);
      }
      if (tid == 0) {
        L.f.sIdx[it] = wi;
        L.f.cbuf[it & 15] = make_float4(qx, qy, qz, 0.f);
      }
    }
    __syncthreads();   // 4-wave barrier
    // final tile flush (rows MC-16..MC-1) + progress = MC
    if (tid < 16) {
      int mrow = MC - 16 + tid;
      float4 cc = L.f.cbuf[tid];
      int r = b*MC + mrow;
      centf[r*3+0] = cc.x; centf[r*3+1] = cc.y; centf[r*3+2] = cc.z;
      if (tid == 0)
        __hip_atomic_store(progress + b, MC, __ATOMIC_RELEASE, __HIP_MEMORY_SCOPE_AGENT);
    }
    // epilogue: out_cent / out_bsel from sIdx (off the critical path; 256 threads)
    for (int m2_ = tid; m2_ < MC; m2_ += 256) {
      int i = L.f.sIdx[m2_];
      int r = b*MC + m2_;
      out_cent[r*3+0] = L.f.px[i]; out_cent[r*3+1] = L.f.py[i]; out_cent[r*3+2] = L.f.pz[i];
      out_bsel[r] = (float)b;
    }
    return;
  }

  // ============ persistent workers: ball query + stage-1 per centroid (512 thr)
  for (;;) {
    if (tid == 0) {
      int t = atomicAdd(taskctr, 1);
      L.w.task = t;
      if (t < NTASK) {
        int m = t >> 3, b = t & 7;
        while (__hip_atomic_load(progress + b, __ATOMIC_ACQUIRE, __HIP_MEMORY_SCOPE_AGENT) < m + 1)
          __builtin_amdgcn_s_sleep(8);
        int bm = b*MC + m;
        L.w.cxyz[0] = __hip_atomic_load(centf + bm*3 + 0, __ATOMIC_RELAXED, __HIP_MEMORY_SCOPE_AGENT);
        L.w.cxyz[1] = __hip_atomic_load(centf + bm*3 + 1, __ATOMIC_RELAXED, __HIP_MEMORY_SCOPE_AGENT);
        L.w.cxyz[2] = __hip_atomic_load(centf + bm*3 + 2, __ATOMIC_RELAXED, __HIP_MEMORY_SCOPE_AGENT);
      }
      L.w.scnt = 0;
    }
    __syncthreads();
    const int t = L.w.task;
    if (t >= NTASK) return;
    const int m = t >> 3, b = t & 7, bm = b*MC + m;
    const float cx = L.w.cxyz[0], cy = L.w.cxyz[1], cz = L.w.cxyz[2];

    // ---- ball query (exact ref semantics)
    for (int i = tid; i < NPTS; i += 512) {
      size_t o = ((size_t)b*NPTS + i)*3;
      float d = d2ref(cx, cy, cz, pos[o], pos[o+1], pos[o+2]);
      if (d <= 0.04f) {
        int p = atomicAdd(&L.w.scnt, 1);
        if (p < CAP) L.w.keys[p] = ((u64)__float_as_uint(d) << 32) | (u32)i;
      }
    }
    __syncthreads();
    int n = L.w.scnt; if (n > CAP) n = CAP;
    int P = 64; while (P < n) P <<= 1;
    for (int i = n + tid; i < P; i += 512) L.w.keys[i] = ~0ull;
    __syncthreads();
    for (int ks = 2; ks <= P; ks <<= 1)
      for (int js = ks >> 1; js > 0; js >>= 1) {
        for (int i = tid; i < P; i += 512) {
          int l = i ^ js;
          if (l > i) {
            u64 a = L.w.keys[i], c = L.w.keys[l];
            bool up = ((i & ks) == 0);
            if ((a > c) == up) { L.w.keys[i] = c; L.w.keys[l] = a; }
          }
        }
        __syncthreads();
      }
    const int c = n < KNB ? n : KNB;
    if (tid < KNB) L.w.nbrS[tid] = (tid < c) ? (int)(u32)(L.w.keys[tid] & 0xffffffffu) : 0;
    if (tid == 0) { cntpc[bm] = c; atomicAdd(cnt_total, c); }
    __syncthreads();

    // ---- stage-1: H = [x_j, p_j - c_i] (64x67) staged in LDS
    {
      const int ge = tid >> 3, qb = tid & 7;
      const float4* xr = (const float4*)(x + ((size_t)(b*NPTS + L.w.nbrS[ge]))*CINV);
      #pragma unroll
      for (int rep = 0; rep < 2; ++rep) {
        int q = qb + rep*8;
        float4 v = xr[q];
        float* d = L.w.Hs + ge*69 + q*4;
        d[0] = v.x; d[1] = v.y; d[2] = v.z; d[3] = v.w;
      }
    }
    if (tid < 64) {
      int row = b*NPTS + L.w.nbrS[tid];
      L.w.Hs[tid*69+64] = pos[(size_t)row*3+0] - cx;
      L.w.Hs[tid*69+65] = pos[(size_t)row*3+1] - cy;
      L.w.Hs[tid*69+66] = pos[(size_t)row*3+2] - cz;
    }
    __syncthreads();

    // ---- GEMM: thread = (edge, col of 8 ch); W via wave-uniform SCALAR loads
    const int edge = tid & 63;
    const int col  = __builtin_amdgcn_readfirstlane(tid >> 6);  // 0..7
    float acc[8];
    #pragma unroll
    for (int j = 0; j < 8; ++j) acc[j] = 0.f;
    const float* hrow = L.w.Hs + edge*69;
    const float* wcol = W1 + col*8;
    for (int k = 0; k < K1; ++k) {
      float hk = hrow[k];
      const float4* w4 = (const float4*)(wcol + k*CH1);
      float4 a = w4[0], bq = w4[1];
      acc[0] = fmaf(hk, a.x,  acc[0]); acc[1] = fmaf(hk, a.y,  acc[1]);
      acc[2] = fmaf(hk, a.z,  acc[2]); acc[3] = fmaf(hk, a.w,  acc[3]);
      acc[4] = fmaf(hk, bq.x, acc[4]); acc[5] = fmaf(hk, bq.y, acc[5]);
      acc[6] = fmaf(hk, bq.z, acc[6]); acc[7] = fmaf(hk, bq.w, acc[7]);
    }
    const bool valid = edge < c;
    #pragma unroll
    for (int j = 0; j < 8; ++j) acc[j] = valid ? acc[j] : 0.f;
    u32* dst = (u32*)(y1g + ((size_t)bm*64 + edge)*CH1 + col*8);
    #pragma unroll
    for (int j = 0; j < 4; ++j)
      dst[j] = (u32)f2bf(acc[2*j]) | ((u32)f2bf(acc[2*j+1]) << 16);
    // group-16 DPP reductions (pure VALU), 4 partials per value
    #pragma unroll
    for (int j = 0; j < 8; ++j) {
      float s = dppsum16(acc[j]);
      float q = dppsum16(acc[j]*acc[j]);
      if ((edge & 15) == 0) {
        L.w.red[col][j][edge>>4]   = s;
        L.w.red[col][8+j][edge>>4] = q;
      }
    }
    __syncthreads();
    const int slot = bm & (NSLOT-1);
    if (tid < 64) {
      float4 g = *(const float4*)&L.w.red[tid>>3][tid&7][0];
      atomicAdd(&Spart[slot*256 + tid], (g.x+g.y)+(g.z+g.w));
    } else if (tid < 128) {
      int cc = tid - 64;
      float4 g = *(const float4*)&L.w.red[cc>>3][8+(cc&7)][0];
      atomicAdd(&Spart[slot*256 + 128 + cc], (g.x+g.y)+(g.z+g.w));
    }
    // top-of-loop __syncthreads() isolates this task's LDS reads from next task's writes
  }
}

// ---------------------------------------------------------------- stage 2: relu(bn1(y1)) @ W2
__global__ __launch_bounds__(256) void k_s2(const u16* __restrict__ y1g,
                                            const float* __restrict__ SC,
                                            const float* __restrict__ W2,
                                            const int* __restrict__ cntpc,
                                            float* __restrict__ Spart,
                                            u16* __restrict__ y2g) {
  __shared__ float Hs[64*65];
  __shared__ float ABs[128];
  __shared__ float red[4][32][4];
  __shared__ int   cntS;
  const int tid = threadIdx.x, bm = blockIdx.x;
  if (tid == 0) cntS = cntpc[bm];
  if (tid < 128) ABs[tid] = SC[tid];            // A1(64) B1(64)
  __syncthreads();
  {
    const u32* yt = (const u32*)y1g + (size_t)bm*2048;  // 64 edges * 32 u32
    #pragma unroll
    for (int rep = 0; rep < 8; ++rep) {
      int g = rep*256 + tid;
      int e = g >> 5, c2 = g & 31, ch = c2*2;
      u32 v = yt[g];
      float lo = fmaxf(fmaf(bf2f((u16)(v & 0xffff)), ABs[ch],   ABs[64+ch]),   0.f);
      float hi = fmaxf(fmaf(bf2f((u16)(v >> 16)),    ABs[ch+1], ABs[64+ch+1]), 0.f);
      Hs[e*65 + ch] = lo; Hs[e*65 + ch + 1] = hi;
    }
  }
  __syncthreads();

  const int edge = tid & 63;
  const int col  = __builtin_amdgcn_readfirstlane(tid >> 6);
  float acc[16];
  #pragma unroll
  for (int j = 0; j < 16; ++j) acc[j] = 0.f;
  const float* hrow = Hs + edge*65;
  const float* wcol = W2 + col*16;
  for (int k = 0; k < CH1; ++k) {
    float hk = hrow[k];
    const float4* w4 = (const float4*)(wcol + k*CH2);
    #pragma unroll
    for (int q = 0; q < 4; ++q) {
      float4 wv = w4[q];
      acc[q*4+0] = fmaf(hk, wv.x, acc[q*4+0]);
      acc[q*4+1] = fmaf(hk, wv.y, acc[q*4+1]);
      acc[q*4+2] = fmaf(hk, wv.z, acc[q*4+2]);
      acc[q*4+3] = fmaf(hk, wv.w, acc[q*4+3]);
    }
  }
  const bool valid = edge < cntS;
  #pragma unroll
  for (int j = 0; j < 16; ++j) acc[j] = valid ? acc[j] : 0.f;
  u32* dst = (u32*)(y2g + ((size_t)bm*64 + edge)*CH2 + col*16);
  #pragma unroll
  for (int j = 0; j < 8; ++j)
    dst[j] = (u32)f2bf(acc[2*j]) | ((u32)f2bf(acc[2*j+1]) << 16);
  #pragma unroll
  for (int j = 0; j < 16; ++j) {
    float s = dppsum16(acc[j]);
    float q = dppsum16(acc[j]*acc[j]);
    if ((edge & 15) == 0) {
      red[col][j][edge>>4]    = s;
      red[col][16+j][edge>>4] = q;
    }
  }
  __syncthreads();
  const int slot = bm & (NSLOT-1);
  if (tid < 64) {
    float4 g = *(const float4*)&red[tid>>4][tid&15][0];
    atomicAdd(&Spart[slot*256 + tid], (g.x+g.y)+(g.z+g.w));
  } else if (tid < 128) {
    int c = tid - 64;
    float4 g = *(const float4*)&red[c>>4][16+(c&15)][0];
    atomicAdd(&Spart[slot*256 + 128 + c], (g.x+g.y)+(g.z+g.w));
  }
}

// ---------------------------------------------------------------- stage 3: relu(bn2(y2)) @ W3, + per-(bm,ch) max/min of f32 y3
__global__ __launch_bounds__(256) void k_s3(const u16* __restrict__ y2g,
                                            const float* __restrict__ SC,
                                            const float* __restrict__ W3,
                                            const int* __restrict__ cntpc,
                                            float* __restrict__ Spart,
                                            float* __restrict__ mxmn) {
  __shared__ float Hs[64*65];
  __shared__ float ABs[128];
  __shared__ float red[4][64][4];
  __shared__ float redm[4][64][4];
  __shared__ int   cntS;
  const int tid = threadIdx.x, bm = blockIdx.x;
  if (tid == 0) cntS = cntpc[bm];
  if (tid < 128) ABs[tid] = SC[128 + tid];      // A2(64) B2(64)
  __syncthreads();
  {
    const u32* yt = (const u32*)y2g + (size_t)bm*2048;
    #pragma unroll
    for (int rep = 0; rep < 8; ++rep) {
      int g = rep*256 + tid;
      int e = g >> 5, c2 = g & 31, ch = c2*2;
      u32 v = yt[g];
      float lo = fmaxf(fmaf(bf2f((u16)(v & 0xffff)), ABs[ch],   ABs[64+ch]),   0.f);
      float hi = fmaxf(fmaf(bf2f((u16)(v >> 16)),    ABs[ch+1], ABs[64+ch+1]), 0.f);
      Hs[e*65 + ch] = lo; Hs[e*65 + ch + 1] = hi;
    }
  }
  __syncthreads();

  const int edge = tid & 63;
  const int col  = __builtin_amdgcn_readfirstlane(tid >> 6);  // owns 32 of 128 ch
  float acc[32];
  #pragma unroll
  for (int j = 0; j < 32; ++j) acc[j] = 0.f;
  const float* hrow = Hs + edge*65;
  const float* wcol = W3 + col*32;
  for (int k = 0; k < CH2; ++k) {
    float hk = hrow[k];
    const float4* w4 = (const float4*)(wcol + k*CH3);
    #pragma unroll
    for (int q = 0; q < 8; ++q) {
      float4 wv = w4[q];
      acc[q*4+0] = fmaf(hk, wv.x, acc[q*4+0]);
      acc[q*4+1] = fmaf(hk, wv.y, acc[q*4+1]);
      acc[q*4+2] = fmaf(hk, wv.z, acc[q*4+2]);
      acc[q*4+3] = fmaf(hk, wv.w, acc[q*4+3]);
    }
  }
  const bool valid = edge < cntS;
  #pragma unroll
  for (int j = 0; j < 32; ++j) {
    float mxv = valid ? acc[j] : -1e30f;
    float mnv = valid ? acc[j] :  1e30f;
    float av  = valid ? acc[j] : 0.f;
    float s  = dppsum16(av);
    float q  = dppsum16(av*av);
    float mx = dppmax16(mxv);
    float mn = dppmin16(mnv);
    if ((edge & 15) == 0) {
      red[col][j][edge>>4]     = s;
      red[col][32+j][edge>>4]  = q;
      redm[col][j][edge>>4]    = mx;
      redm[col][32+j][edge>>4] = mn;
    }
  }
  __syncthreads();
  const int slot = bm & (NSLOT-1);
  if (tid < 128) {
    float4 g = *(const float4*)&red[tid>>5][tid&31][0];
    atomicAdd(&Spart[slot*256 + tid], (g.x+g.y)+(g.z+g.w));
    float4 gm = *(const float4*)&redm[tid>>5][tid&31][0];
    mxmn[(size_t)bm*256 + tid] = fmaxf(fmaxf(gm.x, gm.y), fmaxf(gm.z, gm.w));
  } else {
    int c = tid - 128;
    float4 g = *(const float4*)&red[c>>5][32+(c&31)][0];
    atomicAdd(&Spart[slot*256 + 128 + c], (g.x+g.y)+(g.z+g.w));
    float4 gm = *(const float4*)&redm[c>>5][32+(c&31)][0];
    mxmn[(size_t)bm*256 + 128 + c] = fminf(fminf(gm.x, gm.y), fminf(gm.z, gm.w));
  }
}

// ---------------------------------------------------------------- stage 4: bn3+relu+maxpool from per-block max/min
// max_e relu(a*y+b) = relu(a*max_e(y)+b) for a>0 (monotone correctly-rounded ops
// commute with max); use min_e(y) for a<0. Exact vs the elementwise scan.
__global__ __launch_bounds__(128) void k_s4(const float* __restrict__ mxmn,
                                            const float* __restrict__ SC,
                                            float* __restrict__ out0) {
  const int tid = threadIdx.x, bm = blockIdx.x;
  const float a = SC[256 + tid], b = SC[384 + tid];
  const float mx = mxmn[(size_t)bm*256 + tid];
  const float mn = mxmn[(size_t)bm*256 + 128 + tid];
  const float v = (a > 0.f) ? mx : mn;
  out0[(size_t)bm*CH3 + tid] = fmaxf(fmaf(v, a, b), 0.f);
}

// ---------------------------------------------------------------- finalize
__global__ void k_finalize(const float* __restrict__ Spart,
                           const float* __restrict__ g, const float* __restrict__ bb,
                           const int* __restrict__ cnt_total,
                           float* __restrict__ Aout, float* __restrict__ Bout, int C) {
  int c = threadIdx.x;
  if (c < C) {
    float s = 0.f, q = 0.f;
    for (int sl = 0; sl < NSLOT; ++sl) {
      s += Spart[sl*256 + c];
      q += Spart[sl*256 + 128 + c];
    }
    float n = (float)(*cnt_total); if (n < 1.f) n = 1.f;
    float mu  = s / n;
    float var = q / n - mu*mu; if (var < 0.f) var = 0.f;
    float inv = 1.0f / sqrtf(var + 1e-5f);
    float a = g[c] * inv;
    Aout[c] = a;
    Bout[c] = bb[c] - mu*a;
  }
}

// ---------------------------------------------------------------- host
extern "C" void kernel_launch(void* const* d_in, const int* in_sizes, int n_in,
                              void* d_out, int out_size, void* d_ws, size_t ws_size,
                              hipStream_t stream) {
  (void)in_sizes; (void)n_in; (void)out_size; (void)ws_size;
  const float* x   = (const float*)d_in[0];
  const float* pos = (const float*)d_in[1];
  const float* W1  = (const float*)d_in[3];
  const float* g1  = (const float*)d_in[4];
  const float* b1  = (const float*)d_in[5];
  const float* W2  = (const float*)d_in[6];
  const float* g2  = (const float*)d_in[7];
  const float* b2  = (const float*)d_in[8];
  const float* W3  = (const float*)d_in[9];
  const float* g3  = (const float*)d_in[10];
  const float* b3  = (const float*)d_in[11];

  float* out0     = (float*)d_out;
  float* out_cent = out0 + (size_t)NB*MC*CH3;
  float* out_bsel = out_cent + (size_t)NB*MC*3;

  char* base = (char*)d_ws;
  size_t off = 0;
  auto carve = [&](size_t bytes) -> char* {
    char* p = base + off;
    off = (off + bytes + 255) & ~(size_t)255;
    return p;
  };
  float* centf = (float*)carve(sizeof(float)*NB*MC*3);
  int*   cntpc = (int*)  carve(sizeof(int)*NB*MC);
  char*  zeroblk = carve(256 + 3*NSLOT*256*sizeof(float));
  int*   cnt_total = (int*)zeroblk;
  int*   taskctr   = cnt_total + 1;
  int*   progress  = cnt_total + 2;    // 8 ints
  float* Sp1 = (float*)(zeroblk + 256);
  float* Sp2 = Sp1 + NSLOT*256;
  float* Sp3 = Sp2 + NSLOT*256;
  float* SC = (float*)carve(512*sizeof(float));  // A1 B1 A2 B2 A3(128) B3(128)
  u16* y1g = (u16*)carve((size_t)NE*CH1*2);
  u16* y2g = (u16*)carve((size_t)NE*CH2*2);
  float* mxmn = (float*)carve((size_t)NB*MC*256*sizeof(float));  // 8 MB: max(128) min(128) per bm

  hipMemsetAsync(zeroblk, 0, 256 + 3*NSLOT*256*sizeof(float), stream);
  k_front<<<NBLK, 512, 0, stream>>>(x, pos, centf, out_cent, out_bsel,
                                    W1, Sp1, y1g, cntpc, cnt_total, progress, taskctr);
  k_finalize<<<1, 128, 0, stream>>>(Sp1, g1, b1, cnt_total, SC + 0,   SC + 64,  CH1);
  dim3 sg(NB*MC), sb(256);
  k_s2<<<sg, sb, 0, stream>>>(y1g, SC, W2, cntpc, Sp2, y2g);
  k_finalize<<<1, 128, 0, stream>>>(Sp2, g2, b2, cnt_total, SC + 128, SC + 192, CH2);
  k_s3<<<sg, sb, 0, stream>>>(y2g, SC, W3, cntpc, Sp3, mxmn);
  k_finalize<<<1, 128, 0, stream>>>(Sp3, g3, b3, cnt_total, SC + 256, SC + 384, CH3);
  k_s4<<<sg, 128, 0, stream>>>(mxmn, SC, out0);
}

// Round 11
// 899.968 us; speedup vs baseline: 1.5952x; 1.1533x over previous
//
#include <hip/hip_runtime.h>
#include <stdint.h>

#define NB   8
#define NPTS 4096
#define CINV 64
#define MC   1024
#define KNB  64
#define NE   (NB*MC*KNB)
#define K1   67
#define CH1  64
#define CH2  64
#define CH3  128
#define NSLOT 64
#define CAP  2048
#define NTASK (NB*MC)
#define NBLK 256      // == #CUs

typedef unsigned short u16;
typedef unsigned int   u32;
typedef unsigned long long u64;

using f32x4  = __attribute__((ext_vector_type(4))) float;
using bf16x8 = __attribute__((ext_vector_type(8))) short;

static __device__ __forceinline__ float bf2f(u16 b){ return __uint_as_float(((u32)b)<<16); }
static __device__ __forceinline__ u16  f2bf(float f){
  u32 u = __float_as_uint(f);
  return (u16)((u + 0x7fffu + ((u>>16)&1u)) >> 16);
}
// Exact replica of reference distance: square each diff, sum as (x+y)+z, NO fma contraction.
static __device__ __forceinline__ float d2ref(float ax,float ay,float az,
                                              float bx,float by,float bz){
  float dx = ax-bx, dy = ay-by, dz = az-bz;
  return __fadd_rn(__fadd_rn(__fmul_rn(dx,dx), __fmul_rn(dy,dy)), __fmul_rn(dz,dz));
}
// ---- DPP primitives (pure VALU, no DS pipe) ----
template<int CTRL, int RMASK>
static __device__ __forceinline__ float dppmaxstep(float v){
  int t = __builtin_amdgcn_update_dpp(__float_as_int(v), __float_as_int(v),
                                      CTRL, RMASK, 0xF, false);
  return fmaxf(v, __int_as_float(t));
}
template<int CTRL, int RMASK>
static __device__ __forceinline__ float dppminstep(float v){
  int t = __builtin_amdgcn_update_dpp(__float_as_int(v), __float_as_int(v),
                                      CTRL, RMASK, 0xF, false);
  return fminf(v, __int_as_float(t));
}
template<int CTRL, int RMASK>
static __device__ __forceinline__ float dppaddstep(float v){
  // old = 0 so lanes with masked/invalid source add 0 (exact-once summation)
  int t = __builtin_amdgcn_update_dpp(0, __float_as_int(v), CTRL, RMASK, 0xF, false);
  return v + __int_as_float(t);
}
// Group-16 reductions (4 steps); EVERY lane ends with its 16-lane-group result.
static __device__ __forceinline__ float dppsum16(float v){
  v = dppaddstep<0xB1,0xF>(v); v = dppaddstep<0x4E,0xF>(v);
  v = dppaddstep<0x141,0xF>(v); v = dppaddstep<0x140,0xF>(v);
  return v;
}
// ---- f64-keyed argmax: key = bits[dist(f32) : ~idx]. Both positive doubles,
// so IEEE f64 ordering == u64 bit ordering: v_max_f64 == (max dist, lowest idx on tie).
static __device__ __forceinline__ double kpack(float d, int ni){
  return __hiloint2double(__float_as_int(d), ni);
}
template<int CTRL, int RMASK>
static __device__ __forceinline__ double dppk64(double k){
  int hi = __double2hiint(k), lo = __double2loint(k);
  int thi = __builtin_amdgcn_update_dpp(hi, hi, CTRL, RMASK, 0xF, false);
  int tlo = __builtin_amdgcn_update_dpp(lo, lo, CTRL, RMASK, 0xF, false);
  return fmax(k, __hiloint2double(thi, tlo));
}

// ---------------------------------------------------------------- fused front kernel
struct FpsL {
  float px[NPTS], py[NPTS], pz[NPTS];
  int   sIdx[MC];
  double candD[8];   // keyed candidates, double-buffered 2x4
  float4 cbuf[16];   // centroid staging: flush 16 rows per tile to global
};
struct WkL {
  u64   keys[CAP];        // ball-query sort keys
  float Hs[64*69];        // stage-1 H tile (odd pitch)
  int   nbrS[64];
  float red[8][16][4];    // [col][s(8)+q(8)][group16]
  float cxyz[3];
  int   scnt;
  int   task;
};
union FrontL { FpsL f; WkL w; };

__global__ __launch_bounds__(512) void k_front(const float* __restrict__ x,
                                               const float* __restrict__ pos,
                                               float* __restrict__ centf,
                                               float* __restrict__ out_cent,
                                               float* __restrict__ out_bsel,
                                               const float* __restrict__ W1,
                                               float* __restrict__ Spart,
                                               u16* __restrict__ y1g,
                                               int* __restrict__ cntpc,
                                               int* __restrict__ cnt_total,
                                               int* __restrict__ progress,
                                               int* __restrict__ taskctr) {
  __shared__ FrontL L;
  const int tid = threadIdx.x;

  if (blockIdx.x < NB) {
    // ============ FPS producer: stage with 8 waves, then waves 4-7 EXIT.
    // 4 waves (one per SIMD), 16 pts/lane scalar scan, f64-keyed argmax.
    const int b = blockIdx.x;
    for (int i = tid; i < NPTS; i += 512) {
      size_t o = ((size_t)b*NPTS + i)*3;
      L.f.px[i] = pos[o]; L.f.py[i] = pos[o+1]; L.f.pz[i] = pos[o+2];
    }
    __syncthreads();          // 8-wave barrier (staging)
    if (tid >= 256) return;   // narrow the workgroup: barriers below sync 4 waves

    float cxr[16], cyr[16], czr[16], dist[16];
    int nio[16];
    #pragma unroll
    for (int j = 0; j < 16; ++j) {
      int p = tid*16 + j;
      cxr[j] = L.f.px[p]; cyr[j] = L.f.py[p]; czr[j] = L.f.pz[p];
      dist[j] = 1e10f;
      nio[j] = ~p;
    }
    const int lane = tid & 63, w = tid >> 6;   // w in 0..3
    float qx = L.f.px[0], qy = L.f.py[0], qz = L.f.pz[0];
    if (tid == 0) {
      L.f.sIdx[0] = 0;
      L.f.cbuf[0] = make_float4(qx, qy, qz, 0.f);
    }

    for (int it = 1; it < MC; ++it) {
      // ---- scan: pure min, no compares, no vcc
      #pragma unroll
      for (int j = 0; j < 16; ++j) {
        float d = d2ref(cxr[j], cyr[j], czr[j], qx, qy, qz);
        dist[j] = fminf(dist[j], d);
      }
      // ---- keyed pairwise tree over 16 points (15 x v_max_f64)
      double t0 = fmax(kpack(dist[0],  nio[0]),  kpack(dist[1],  nio[1]));
      double t1 = fmax(kpack(dist[2],  nio[2]),  kpack(dist[3],  nio[3]));
      double t2 = fmax(kpack(dist[4],  nio[4]),  kpack(dist[5],  nio[5]));
      double t3 = fmax(kpack(dist[6],  nio[6]),  kpack(dist[7],  nio[7]));
      double t4 = fmax(kpack(dist[8],  nio[8]),  kpack(dist[9],  nio[9]));
      double t5 = fmax(kpack(dist[10], nio[10]), kpack(dist[11], nio[11]));
      double t6 = fmax(kpack(dist[12], nio[12]), kpack(dist[13], nio[13]));
      double t7 = fmax(kpack(dist[14], nio[14]), kpack(dist[15], nio[15]));
      double u0 = fmax(t0, t1), u1 = fmax(t2, t3), u2 = fmax(t4, t5), u3 = fmax(t6, t7);
      double bk = fmax(fmax(u0, u1), fmax(u2, u3));
      // ---- wave keyed reduce (6 DPP steps), winner key valid in lane 63
      bk = dppk64<0xB1,0xF>(bk);
      bk = dppk64<0x4E,0xF>(bk);
      bk = dppk64<0x141,0xF>(bk);
      bk = dppk64<0x140,0xF>(bk);
      bk = dppk64<0x142,0xA>(bk);
      bk = dppk64<0x143,0xC>(bk);
      if (lane == 63) L.f.candD[(it & 1)*4 + w] = bk;
      __syncthreads();   // 4-wave barrier
      // ---- resolve 4 candidates branch-free (2 keyed DPP steps, all lanes uniform)
      double ck = L.f.candD[(it & 1)*4 + (lane & 3)];
      ck = dppk64<0xB1,0xF>(ck);
      ck = dppk64<0x4E,0xF>(ck);
      int wi = (int)(~(u32)__double2loint(ck));   // winning point index (uniform)
      qx = L.f.px[wi]; qy = L.f.py[wi]; qz = L.f.pz[wi];   // broadcast LDS reads
      // flush PREVIOUS 16-row tile then release-publish progress
      if ((it & 15) == 0 && tid < 16) {
        int mrow = it - 16 + tid;
        float4 cc = L.f.cbuf[tid];
        int r = b*MC + mrow;
        centf[r*3+0] = cc.x; centf[r*3+1] = cc.y; centf[r*3+2] = cc.z;
        if (tid == 0)
          __hip_atomic_store(progress + b, it, __ATOMIC_RELEASE, __HIP_MEMORY_SCOPE_AGENT);
      }
      if (tid == 0) {
        L.f.sIdx[it] = wi;
        L.f.cbuf[it & 15] = make_float4(qx, qy, qz, 0.f);
      }
    }
    __syncthreads();   // 4-wave barrier
    // final tile flush (rows MC-16..MC-1) + progress = MC
    if (tid < 16) {
      int mrow = MC - 16 + tid;
      float4 cc = L.f.cbuf[tid];
      int r = b*MC + mrow;
      centf[r*3+0] = cc.x; centf[r*3+1] = cc.y; centf[r*3+2] = cc.z;
      if (tid == 0)
        __hip_atomic_store(progress + b, MC, __ATOMIC_RELEASE, __HIP_MEMORY_SCOPE_AGENT);
    }
    // epilogue: out_cent / out_bsel from sIdx (off the critical path; 256 threads)
    for (int m2_ = tid; m2_ < MC; m2_ += 256) {
      int i = L.f.sIdx[m2_];
      int r = b*MC + m2_;
      out_cent[r*3+0] = L.f.px[i]; out_cent[r*3+1] = L.f.py[i]; out_cent[r*3+2] = L.f.pz[i];
      out_bsel[r] = (float)b;
    }
    return;
  }

  // ============ persistent workers: ball query + stage-1 per centroid (512 thr)
  for (;;) {
    if (tid == 0) {
      int t = atomicAdd(taskctr, 1);
      L.w.task = t;
      if (t < NTASK) {
        int m = t >> 3, b = t & 7;
        while (__hip_atomic_load(progress + b, __ATOMIC_ACQUIRE, __HIP_MEMORY_SCOPE_AGENT) < m + 1)
          __builtin_amdgcn_s_sleep(8);
        int bm = b*MC + m;
        L.w.cxyz[0] = __hip_atomic_load(centf + bm*3 + 0, __ATOMIC_RELAXED, __HIP_MEMORY_SCOPE_AGENT);
        L.w.cxyz[1] = __hip_atomic_load(centf + bm*3 + 1, __ATOMIC_RELAXED, __HIP_MEMORY_SCOPE_AGENT);
        L.w.cxyz[2] = __hip_atomic_load(centf + bm*3 + 2, __ATOMIC_RELAXED, __HIP_MEMORY_SCOPE_AGENT);
      }
      L.w.scnt = 0;
    }
    __syncthreads();
    const int t = L.w.task;
    if (t >= NTASK) return;
    const int m = t >> 3, b = t & 7, bm = b*MC + m;
    const float cx = L.w.cxyz[0], cy = L.w.cxyz[1], cz = L.w.cxyz[2];

    // ---- ball query (exact ref semantics)
    for (int i = tid; i < NPTS; i += 512) {
      size_t o = ((size_t)b*NPTS + i)*3;
      float d = d2ref(cx, cy, cz, pos[o], pos[o+1], pos[o+2]);
      if (d <= 0.04f) {
        int p = atomicAdd(&L.w.scnt, 1);
        if (p < CAP) L.w.keys[p] = ((u64)__float_as_uint(d) << 32) | (u32)i;
      }
    }
    __syncthreads();
    int n = L.w.scnt; if (n > CAP) n = CAP;
    int P = 64; while (P < n) P <<= 1;
    for (int i = n + tid; i < P; i += 512) L.w.keys[i] = ~0ull;
    __syncthreads();
    for (int ks = 2; ks <= P; ks <<= 1)
      for (int js = ks >> 1; js > 0; js >>= 1) {
        for (int i = tid; i < P; i += 512) {
          int l = i ^ js;
          if (l > i) {
            u64 a = L.w.keys[i], c = L.w.keys[l];
            bool up = ((i & ks) == 0);
            if ((a > c) == up) { L.w.keys[i] = c; L.w.keys[l] = a; }
          }
        }
        __syncthreads();
      }
    const int c = n < KNB ? n : KNB;
    if (tid < KNB) L.w.nbrS[tid] = (tid < c) ? (int)(u32)(L.w.keys[tid] & 0xffffffffu) : 0;
    if (tid == 0) { cntpc[bm] = c; atomicAdd(cnt_total, c); }
    __syncthreads();

    // ---- stage-1: H = [x_j, p_j - c_i] (64x67) staged in LDS
    {
      const int ge = tid >> 3, qb = tid & 7;
      const float4* xr = (const float4*)(x + ((size_t)(b*NPTS + L.w.nbrS[ge]))*CINV);
      #pragma unroll
      for (int rep = 0; rep < 2; ++rep) {
        int q = qb + rep*8;
        float4 v = xr[q];
        float* d = L.w.Hs + ge*69 + q*4;
        d[0] = v.x; d[1] = v.y; d[2] = v.z; d[3] = v.w;
      }
    }
    if (tid < 64) {
      int row = b*NPTS + L.w.nbrS[tid];
      L.w.Hs[tid*69+64] = pos[(size_t)row*3+0] - cx;
      L.w.Hs[tid*69+65] = pos[(size_t)row*3+1] - cy;
      L.w.Hs[tid*69+66] = pos[(size_t)row*3+2] - cz;
    }
    __syncthreads();

    // ---- GEMM: thread = (edge, col of 8 ch); W via wave-uniform SCALAR loads
    const int edge = tid & 63;
    const int col  = __builtin_amdgcn_readfirstlane(tid >> 6);  // 0..7
    float acc[8];
    #pragma unroll
    for (int j = 0; j < 8; ++j) acc[j] = 0.f;
    const float* hrow = L.w.Hs + edge*69;
    const float* wcol = W1 + col*8;
    for (int k = 0; k < K1; ++k) {
      float hk = hrow[k];
      const float4* w4 = (const float4*)(wcol + k*CH1);
      float4 a = w4[0], bq = w4[1];
      acc[0] = fmaf(hk, a.x,  acc[0]); acc[1] = fmaf(hk, a.y,  acc[1]);
      acc[2] = fmaf(hk, a.z,  acc[2]); acc[3] = fmaf(hk, a.w,  acc[3]);
      acc[4] = fmaf(hk, bq.x, acc[4]); acc[5] = fmaf(hk, bq.y, acc[5]);
      acc[6] = fmaf(hk, bq.z, acc[6]); acc[7] = fmaf(hk, bq.w, acc[7]);
    }
    const bool valid = edge < c;
    #pragma unroll
    for (int j = 0; j < 8; ++j) acc[j] = valid ? acc[j] : 0.f;
    u32* dst = (u32*)(y1g + ((size_t)bm*64 + edge)*CH1 + col*8);
    #pragma unroll
    for (int j = 0; j < 4; ++j)
      dst[j] = (u32)f2bf(acc[2*j]) | ((u32)f2bf(acc[2*j+1]) << 16);
    // group-16 DPP reductions (pure VALU), 4 partials per value
    #pragma unroll
    for (int j = 0; j < 8; ++j) {
      float s = dppsum16(acc[j]);
      float q = dppsum16(acc[j]*acc[j]);
      if ((edge & 15) == 0) {
        L.w.red[col][j][edge>>4]   = s;
        L.w.red[col][8+j][edge>>4] = q;
      }
    }
    __syncthreads();
    const int slot = bm & (NSLOT-1);
    if (tid < 64) {
      float4 g = *(const float4*)&L.w.red[tid>>3][tid&7][0];
      atomicAdd(&Spart[slot*256 + tid], (g.x+g.y)+(g.z+g.w));
    } else if (tid < 128) {
      int cc = tid - 64;
      float4 g = *(const float4*)&L.w.red[cc>>3][8+(cc&7)][0];
      atomicAdd(&Spart[slot*256 + 128 + cc], (g.x+g.y)+(g.z+g.w));
    }
    // top-of-loop __syncthreads() isolates this task's LDS reads from next task's writes
  }
}

// ---------------------------------------------------------------- stage 2: relu(bn1(y1)) @ W2
__global__ __launch_bounds__(256) void k_s2(const u16* __restrict__ y1g,
                                            const float* __restrict__ SC,
                                            const float* __restrict__ W2,
                                            const int* __restrict__ cntpc,
                                            float* __restrict__ Spart,
                                            u16* __restrict__ y2g) {
  __shared__ float Hs[64*65];
  __shared__ float ABs[128];
  __shared__ float red[4][32][4];
  __shared__ int   cntS;
  const int tid = threadIdx.x, bm = blockIdx.x;
  if (tid == 0) cntS = cntpc[bm];
  if (tid < 128) ABs[tid] = SC[tid];            // A1(64) B1(64)
  __syncthreads();
  {
    const u32* yt = (const u32*)y1g + (size_t)bm*2048;  // 64 edges * 32 u32
    #pragma unroll
    for (int rep = 0; rep < 8; ++rep) {
      int g = rep*256 + tid;
      int e = g >> 5, c2 = g & 31, ch = c2*2;
      u32 v = yt[g];
      float lo = fmaxf(fmaf(bf2f((u16)(v & 0xffff)), ABs[ch],   ABs[64+ch]),   0.f);
      float hi = fmaxf(fmaf(bf2f((u16)(v >> 16)),    ABs[ch+1], ABs[64+ch+1]), 0.f);
      Hs[e*65 + ch] = lo; Hs[e*65 + ch + 1] = hi;
    }
  }
  __syncthreads();

  const int edge = tid & 63;
  const int col  = __builtin_amdgcn_readfirstlane(tid >> 6);
  float acc[16];
  #pragma unroll
  for (int j = 0; j < 16; ++j) acc[j] = 0.f;
  const float* hrow = Hs + edge*65;
  const float* wcol = W2 + col*16;
  for (int k = 0; k < CH1; ++k) {
    float hk = hrow[k];
    const float4* w4 = (const float4*)(wcol + k*CH2);
    #pragma unroll
    for (int q = 0; q < 4; ++q) {
      float4 wv = w4[q];
      acc[q*4+0] = fmaf(hk, wv.x, acc[q*4+0]);
      acc[q*4+1] = fmaf(hk, wv.y, acc[q*4+1]);
      acc[q*4+2] = fmaf(hk, wv.z, acc[q*4+2]);
      acc[q*4+3] = fmaf(hk, wv.w, acc[q*4+3]);
    }
  }
  const bool valid = edge < cntS;
  #pragma unroll
  for (int j = 0; j < 16; ++j) acc[j] = valid ? acc[j] : 0.f;
  u32* dst = (u32*)(y2g + ((size_t)bm*64 + edge)*CH2 + col*16);
  #pragma unroll
  for (int j = 0; j < 8; ++j)
    dst[j] = (u32)f2bf(acc[2*j]) | ((u32)f2bf(acc[2*j+1]) << 16);
  #pragma unroll
  for (int j = 0; j < 16; ++j) {
    float s = dppsum16(acc[j]);
    float q = dppsum16(acc[j]*acc[j]);
    if ((edge & 15) == 0) {
      red[col][j][edge>>4]    = s;
      red[col][16+j][edge>>4] = q;
    }
  }
  __syncthreads();
  const int slot = bm & (NSLOT-1);
  if (tid < 64) {
    float4 g = *(const float4*)&red[tid>>4][tid&15][0];
    atomicAdd(&Spart[slot*256 + tid], (g.x+g.y)+(g.z+g.w));
  } else if (tid < 128) {
    int c = tid - 64;
    float4 g = *(const float4*)&red[c>>4][16+(c&15)][0];
    atomicAdd(&Spart[slot*256 + 128 + c], (g.x+g.y)+(g.z+g.w));
  }
}

// ---------------------------------------------------------------- W3 -> bf16 MFMA-fragment layout
// tile T = globalNt*2 + Kt (globalNt 0..7 over 128 ch, Kt 0..1 over K=64).
// lane l supplies B[k][n]: n = globalNt*16 + (l&15), k = Kt*32 + (l>>4)*8 + j.
__global__ void k_wconv(const float* __restrict__ W3, u16* __restrict__ W3f) {
  int t = blockIdx.x*256 + threadIdx.x;     // 32 blocks x 256 = 8192
  int T = t >> 9, lane = (t >> 3) & 63, j = t & 7;
  int n = (T >> 1)*16 + (lane & 15);
  int k = (T & 1)*32 + (lane >> 4)*8 + j;
  W3f[t] = f2bf(W3[k*CH3 + n]);
}

// ---------------------------------------------------------------- stage 3 (MFMA): relu(bn2(y2)) @ W3
// wave wv owns 32 output channels (2 N-tiles of 16); M=64 edges = 4 M-tiles; K=64 = 2 K-tiles.
// C/D layout (verified): col = lane&15, row = (lane>>4)*4 + reg.
__global__ __launch_bounds__(256) void k_s3(const u16* __restrict__ y2g,
                                            const float* __restrict__ SC,
                                            const u16* __restrict__ W3f,
                                            const int* __restrict__ cntpc,
                                            float* __restrict__ Spart,
                                            float* __restrict__ mxmn) {
  __shared__ u16   Hb[64*72];      // bf16 h2, pitch 72 (144B rows: 16B-aligned, 2-way banks)
  __shared__ float ABs[128];
  __shared__ float redS[4][32][4];
  __shared__ float redQ[4][32][4];
  __shared__ float redM[4][32][4];
  __shared__ float redN[4][32][4];
  __shared__ int   cntS;
  const int tid = threadIdx.x, bm = blockIdx.x;
  if (tid == 0) cntS = cntpc[bm];
  if (tid < 128) ABs[tid] = SC[128 + tid];      // A2(64) B2(64)
  __syncthreads();
  {
    const u32* yt = (const u32*)y2g + (size_t)bm*2048;
    #pragma unroll
    for (int rep = 0; rep < 8; ++rep) {
      int g = rep*256 + tid;
      int e = g >> 5, ch = (g & 31)*2;
      u32 v = yt[g];
      float lo = fmaxf(fmaf(bf2f((u16)(v & 0xffff)), ABs[ch],   ABs[64+ch]),   0.f);
      float hi = fmaxf(fmaf(bf2f((u16)(v >> 16)),    ABs[ch+1], ABs[64+ch+1]), 0.f);
      *(u32*)&Hb[e*72 + ch] = (u32)f2bf(lo) | ((u32)f2bf(hi) << 16);
    }
  }
  __syncthreads();

  const int lane = tid & 63;
  const int wv   = __builtin_amdgcn_readfirstlane(tid >> 6);  // 0..3
  const int r16  = lane & 15, g4 = lane >> 4;
  const int cnt  = cntS;

  // B fragments (global, L2-hot, fragment-ready)
  bf16x8 bfr[2][2];
  #pragma unroll
  for (int Nt = 0; Nt < 2; ++Nt)
    #pragma unroll
    for (int Kt = 0; Kt < 2; ++Kt)
      bfr[Nt][Kt] = *(const bf16x8*)&W3f[(((wv*2 + Nt)*2 + Kt)*64 + lane)*8];

  f32x4 acc[4][2];
  #pragma unroll
  for (int Mt = 0; Mt < 4; ++Mt)
    #pragma unroll
    for (int Nt = 0; Nt < 2; ++Nt)
      acc[Mt][Nt] = (f32x4){0.f, 0.f, 0.f, 0.f};

  #pragma unroll
  for (int Kt = 0; Kt < 2; ++Kt) {
    #pragma unroll
    for (int Mt = 0; Mt < 4; ++Mt) {
      // A fragment: row = Mt*16 + r16, k = Kt*32 + g4*8 + j (contiguous b128)
      bf16x8 afr = *(const bf16x8*)&Hb[(Mt*16 + r16)*72 + Kt*32 + g4*8];
      #pragma unroll
      for (int Nt = 0; Nt < 2; ++Nt)
        acc[Mt][Nt] = __builtin_amdgcn_mfma_f32_16x16x32_bf16(afr, bfr[Nt][Kt],
                                                              acc[Mt][Nt], 0, 0, 0);
    }
  }

  // epilogue: lane holds channel n = wv*32 + Nt*16 + r16; rows Mt*16 + g4*4 + rr in-lane.
  #pragma unroll
  for (int Nt = 0; Nt < 2; ++Nt) {
    float s = 0.f, q = 0.f, mx = -1e30f, mn = 1e30f;
    #pragma unroll
    for (int Mt = 0; Mt < 4; ++Mt) {
      #pragma unroll
      for (int rr = 0; rr < 4; ++rr) {
        int row = Mt*16 + g4*4 + rr;
        float v = acc[Mt][Nt][rr];
        bool valid = row < cnt;
        float av = valid ? v : 0.f;
        s += av; q = fmaf(av, av, q);
        mx = fmaxf(mx, valid ? v : -1e30f);
        mn = fminf(mn, valid ? v :  1e30f);
      }
    }
    redS[wv][Nt*16 + r16][g4] = s;
    redQ[wv][Nt*16 + r16][g4] = q;
    redM[wv][Nt*16 + r16][g4] = mx;
    redN[wv][Nt*16 + r16][g4] = mn;
  }
  __syncthreads();
  const int slot = bm & (NSLOT-1);
  if (tid < 128) {
    float4 g = *(const float4*)&redS[tid>>5][tid&31][0];
    atomicAdd(&Spart[slot*256 + tid], (g.x+g.y)+(g.z+g.w));
    float4 gm = *(const float4*)&redM[tid>>5][tid&31][0];
    mxmn[(size_t)bm*256 + tid] = fmaxf(fmaxf(gm.x, gm.y), fmaxf(gm.z, gm.w));
  } else {
    int c = tid - 128;
    float4 g = *(const float4*)&redQ[c>>5][c&31][0];
    atomicAdd(&Spart[slot*256 + 128 + c], (g.x+g.y)+(g.z+g.w));
    float4 gm = *(const float4*)&redN[c>>5][c&31][0];
    mxmn[(size_t)bm*256 + 128 + c] = fminf(fminf(gm.x, gm.y), fminf(gm.z, gm.w));
  }
}

// ---------------------------------------------------------------- stage 4: bn3+relu+maxpool from per-block max/min
// max_e relu(a*y+b) = relu(a*max_e(y)+b) for a>0 (monotone correctly-rounded ops
// commute with max); use min_e(y) for a<0. Exact vs the elementwise scan.
__global__ __launch_bounds__(128) void k_s4(const float* __restrict__ mxmn,
                                            const float* __restrict__ SC,
                                            float* __restrict__ out0) {
  const int tid = threadIdx.x, bm = blockIdx.x;
  const float a = SC[256 + tid], b = SC[384 + tid];
  const float mx = mxmn[(size_t)bm*256 + tid];
  const float mn = mxmn[(size_t)bm*256 + 128 + tid];
  const float v = (a > 0.f) ? mx : mn;
  out0[(size_t)bm*CH3 + tid] = fmaxf(fmaf(v, a, b), 0.f);
}

// ---------------------------------------------------------------- finalize
__global__ void k_finalize(const float* __restrict__ Spart,
                           const float* __restrict__ g, const float* __restrict__ bb,
                           const int* __restrict__ cnt_total,
                           float* __restrict__ Aout, float* __restrict__ Bout, int C) {
  int c = threadIdx.x;
  if (c < C) {
    float s = 0.f, q = 0.f;
    for (int sl = 0; sl < NSLOT; ++sl) {
      s += Spart[sl*256 + c];
      q += Spart[sl*256 + 128 + c];
    }
    float n = (float)(*cnt_total); if (n < 1.f) n = 1.f;
    float mu  = s / n;
    float var = q / n - mu*mu; if (var < 0.f) var = 0.f;
    float inv = 1.0f / sqrtf(var + 1e-5f);
    float a = g[c] * inv;
    Aout[c] = a;
    Bout[c] = bb[c] - mu*a;
  }
}

// ---------------------------------------------------------------- host
extern "C" void kernel_launch(void* const* d_in, const int* in_sizes, int n_in,
                              void* d_out, int out_size, void* d_ws, size_t ws_size,
                              hipStream_t stream) {
  (void)in_sizes; (void)n_in; (void)out_size; (void)ws_size;
  const float* x   = (const float*)d_in[0];
  const float* pos = (const float*)d_in[1];
  const float* W1  = (const float*)d_in[3];
  const float* g1  = (const float*)d_in[4];
  const float* b1  = (const float*)d_in[5];
  const float* W2  = (const float*)d_in[6];
  const float* g2  = (const float*)d_in[7];
  const float* b2  = (const float*)d_in[8];
  const float* W3  = (const float*)d_in[9];
  const float* g3  = (const float*)d_in[10];
  const float* b3  = (const float*)d_in[11];

  float* out0     = (float*)d_out;
  float* out_cent = out0 + (size_t)NB*MC*CH3;
  float* out_bsel = out_cent + (size_t)NB*MC*3;

  char* base = (char*)d_ws;
  size_t off = 0;
  auto carve = [&](size_t bytes) -> char* {
    char* p = base + off;
    off = (off + bytes + 255) & ~(size_t)255;
    return p;
  };
  float* centf = (float*)carve(sizeof(float)*NB*MC*3);
  int*   cntpc = (int*)  carve(sizeof(int)*NB*MC);
  char*  zeroblk = carve(256 + 3*NSLOT*256*sizeof(float));
  int*   cnt_total = (int*)zeroblk;
  int*   taskctr   = cnt_total + 1;
  int*   progress  = cnt_total + 2;    // 8 ints
  float* Sp1 = (float*)(zeroblk + 256);
  float* Sp2 = Sp1 + NSLOT*256;
  float* Sp3 = Sp2 + NSLOT*256;
  float* SC = (float*)carve(512*sizeof(float));  // A1 B1 A2 B2 A3(128) B3(128)
  u16* y1g = (u16*)carve((size_t)NE*CH1*2);
  u16* y2g = (u16*)carve((size_t)NE*CH2*2);
  float* mxmn = (float*)carve((size_t)NB*MC*256*sizeof(float));  // 8 MB
  u16* W3f = (u16*)carve(16*64*8*sizeof(u16));   // 16 KB fragment-ready W3 (bf16)

  hipMemsetAsync(zeroblk, 0, 256 + 3*NSLOT*256*sizeof(float), stream);
  k_wconv<<<32, 256, 0, stream>>>(W3, W3f);
  k_front<<<NBLK, 512, 0, stream>>>(x, pos, centf, out_cent, out_bsel,
                                    W1, Sp1, y1g, cntpc, cnt_total, progress, taskctr);
  k_finalize<<<1, 128, 0, stream>>>(Sp1, g1, b1, cnt_total, SC + 0,   SC + 64,  CH1);
  dim3 sg(NB*MC), sb(256);
  k_s2<<<sg, sb, 0, stream>>>(y1g, SC, W2, cntpc, Sp2, y2g);
  k_finalize<<<1, 128, 0, stream>>>(Sp2, g2, b2, cnt_total, SC + 128, SC + 192, CH2);
  k_s3<<<sg, sb, 0, stream>>>(y2g, SC, W3f, cntpc, Sp3, mxmn);
  k_finalize<<<1, 128, 0, stream>>>(Sp3, g3, b3, cnt_total, SC + 256, SC + 384, CH3);
  k_s4<<<sg, 128, 0, stream>>>(mxmn, SC, out0);
}

// Round 12
// 849.366 us; speedup vs baseline: 1.6902x; 1.0596x over previous
//
#include <hip/hip_runtime.h>
#include <stdint.h>

#define NB   8
#define NPTS 4096
#define CINV 64
#define MC   1024
#define KNB  64
#define NE   (NB*MC*KNB)
#define K1   67
#define CH1  64
#define CH2  64
#define CH3  128
#define NSLOT 64
#define CAP  2048
#define NTASK (NB*MC)
#define NBLK 256      // == #CUs

typedef unsigned short u16;
typedef unsigned int   u32;
typedef unsigned long long u64;

using f32x4  = __attribute__((ext_vector_type(4))) float;
using bf16x8 = __attribute__((ext_vector_type(8))) short;

static __device__ __forceinline__ float bf2f(u16 b){ return __uint_as_float(((u32)b)<<16); }
static __device__ __forceinline__ u16  f2bf(float f){
  u32 u = __float_as_uint(f);
  return (u16)((u + 0x7fffu + ((u>>16)&1u)) >> 16);
}
// Exact replica of reference distance: square each diff, sum as (x+y)+z, NO fma contraction.
static __device__ __forceinline__ float d2ref(float ax,float ay,float az,
                                              float bx,float by,float bz){
  float dx = ax-bx, dy = ay-by, dz = az-bz;
  return __fadd_rn(__fadd_rn(__fmul_rn(dx,dx), __fmul_rn(dy,dy)), __fmul_rn(dz,dz));
}
// ---- DPP primitives (pure VALU, no DS pipe) ----
template<int CTRL, int RMASK>
static __device__ __forceinline__ float dppaddstep(float v){
  // old = 0 so lanes with masked/invalid source add 0 (exact-once summation)
  int t = __builtin_amdgcn_update_dpp(0, __float_as_int(v), CTRL, RMASK, 0xF, false);
  return v + __int_as_float(t);
}
// Group-16 reductions (4 steps); EVERY lane ends with its 16-lane-group result.
static __device__ __forceinline__ float dppsum16(float v){
  v = dppaddstep<0xB1,0xF>(v); v = dppaddstep<0x4E,0xF>(v);
  v = dppaddstep<0x141,0xF>(v); v = dppaddstep<0x140,0xF>(v);
  return v;
}
// ---- f64-keyed argmax: key = bits[dist(f32) : ~idx]. Both positive doubles,
// so IEEE f64 ordering == u64 bit ordering: v_max_f64 == (max dist, lowest idx on tie).
static __device__ __forceinline__ double kpack(float d, int ni){
  return __hiloint2double(__float_as_int(d), ni);
}
template<int CTRL, int RMASK>
static __device__ __forceinline__ double dppk64(double k){
  int hi = __double2hiint(k), lo = __double2loint(k);
  int thi = __builtin_amdgcn_update_dpp(hi, hi, CTRL, RMASK, 0xF, false);
  int tlo = __builtin_amdgcn_update_dpp(lo, lo, CTRL, RMASK, 0xF, false);
  return fmax(k, __hiloint2double(thi, tlo));
}

// ---------------------------------------------------------------- fused front kernel
struct FpsL {
  float px[NPTS], py[NPTS], pz[NPTS];
  int   sIdx[MC];
  double candD[8];   // keyed candidates, double-buffered 2x4
  float4 cbuf[16];   // centroid staging: flush 16 rows per tile to global
};
struct WkL {
  u64   keys[CAP];        // ball-query sort keys
  float Hs[64*69];        // stage-1 H tile (odd pitch)
  int   nbrS[64];
  float red[8][16][4];    // [col][s(8)+q(8)][group16]
  float cxyz[3];
  int   scnt;
  int   task;
};
union FrontL { FpsL f; WkL w; };

__global__ __launch_bounds__(512) void k_front(const float* __restrict__ x,
                                               const float* __restrict__ pos,
                                               float* __restrict__ centf,
                                               float* __restrict__ out_cent,
                                               float* __restrict__ out_bsel,
                                               const float* __restrict__ W1,
                                               float* __restrict__ Spart,
                                               u16* __restrict__ y1g,
                                               int* __restrict__ cntpc,
                                               int* __restrict__ cnt_total,
                                               int* __restrict__ progress,
                                               int* __restrict__ taskctr) {
  __shared__ FrontL L;
  const int tid = threadIdx.x;

  if (blockIdx.x < NB) {
    // ============ FPS producer: stage with 8 waves, then waves 4-7 EXIT.
    // 4 waves (one per SIMD), 16 pts/lane scalar scan, f64-keyed argmax.
    const int b = blockIdx.x;
    for (int i = tid; i < NPTS; i += 512) {
      size_t o = ((size_t)b*NPTS + i)*3;
      L.f.px[i] = pos[o]; L.f.py[i] = pos[o+1]; L.f.pz[i] = pos[o+2];
    }
    __syncthreads();          // 8-wave barrier (staging)
    if (tid >= 256) return;   // narrow the workgroup: barriers below sync 4 waves

    float cxr[16], cyr[16], czr[16], dist[16];
    int nio[16];
    #pragma unroll
    for (int j = 0; j < 16; ++j) {
      int p = tid*16 + j;
      cxr[j] = L.f.px[p]; cyr[j] = L.f.py[p]; czr[j] = L.f.pz[p];
      dist[j] = 1e10f;
      nio[j] = ~p;
    }
    const int lane = tid & 63, w = tid >> 6;   // w in 0..3
    float qx = L.f.px[0], qy = L.f.py[0], qz = L.f.pz[0];
    if (tid == 0) {
      L.f.sIdx[0] = 0;
      L.f.cbuf[0] = make_float4(qx, qy, qz, 0.f);
    }

    for (int it = 1; it < MC; ++it) {
      // ---- scan: pure min, no compares, no vcc
      #pragma unroll
      for (int j = 0; j < 16; ++j) {
        float d = d2ref(cxr[j], cyr[j], czr[j], qx, qy, qz);
        dist[j] = fminf(dist[j], d);
      }
      // ---- keyed pairwise tree over 16 points (15 x v_max_f64)
      double t0 = fmax(kpack(dist[0],  nio[0]),  kpack(dist[1],  nio[1]));
      double t1 = fmax(kpack(dist[2],  nio[2]),  kpack(dist[3],  nio[3]));
      double t2 = fmax(kpack(dist[4],  nio[4]),  kpack(dist[5],  nio[5]));
      double t3 = fmax(kpack(dist[6],  nio[6]),  kpack(dist[7],  nio[7]));
      double t4 = fmax(kpack(dist[8],  nio[8]),  kpack(dist[9],  nio[9]));
      double t5 = fmax(kpack(dist[10], nio[10]), kpack(dist[11], nio[11]));
      double t6 = fmax(kpack(dist[12], nio[12]), kpack(dist[13], nio[13]));
      double t7 = fmax(kpack(dist[14], nio[14]), kpack(dist[15], nio[15]));
      double u0 = fmax(t0, t1), u1 = fmax(t2, t3), u2 = fmax(t4, t5), u3 = fmax(t6, t7);
      double bk = fmax(fmax(u0, u1), fmax(u2, u3));
      // ---- wave keyed reduce (6 DPP steps), winner key valid in lane 63
      bk = dppk64<0xB1,0xF>(bk);
      bk = dppk64<0x4E,0xF>(bk);
      bk = dppk64<0x141,0xF>(bk);
      bk = dppk64<0x140,0xF>(bk);
      bk = dppk64<0x142,0xA>(bk);
      bk = dppk64<0x143,0xC>(bk);
      if (lane == 63) L.f.candD[(it & 1)*4 + w] = bk;
      __syncthreads();   // 4-wave barrier
      // ---- resolve 4 candidates branch-free (2 keyed DPP steps, all lanes uniform)
      double ck = L.f.candD[(it & 1)*4 + (lane & 3)];
      ck = dppk64<0xB1,0xF>(ck);
      ck = dppk64<0x4E,0xF>(ck);
      int wi = (int)(~(u32)__double2loint(ck));   // winning point index (uniform)
      qx = L.f.px[wi]; qy = L.f.py[wi]; qz = L.f.pz[wi];   // broadcast LDS reads
      // flush PREVIOUS 16-row tile then release-publish progress
      if ((it & 15) == 0 && tid < 16) {
        int mrow = it - 16 + tid;
        float4 cc = L.f.cbuf[tid];
        int r = b*MC + mrow;
        centf[r*3+0] = cc.x; centf[r*3+1] = cc.y; centf[r*3+2] = cc.z;
        if (tid == 0)
          __hip_atomic_store(progress + b, it, __ATOMIC_RELEASE, __HIP_MEMORY_SCOPE_AGENT);
      }
      if (tid == 0) {
        L.f.sIdx[it] = wi;
        L.f.cbuf[it & 15] = make_float4(qx, qy, qz, 0.f);
      }
    }
    __syncthreads();   // 4-wave barrier
    // final tile flush (rows MC-16..MC-1) + progress = MC
    if (tid < 16) {
      int mrow = MC - 16 + tid;
      float4 cc = L.f.cbuf[tid];
      int r = b*MC + mrow;
      centf[r*3+0] = cc.x; centf[r*3+1] = cc.y; centf[r*3+2] = cc.z;
      if (tid == 0)
        __hip_atomic_store(progress + b, MC, __ATOMIC_RELEASE, __HIP_MEMORY_SCOPE_AGENT);
    }
    // epilogue: out_cent / out_bsel from sIdx (off the critical path; 256 threads)
    for (int m2_ = tid; m2_ < MC; m2_ += 256) {
      int i = L.f.sIdx[m2_];
      int r = b*MC + m2_;
      out_cent[r*3+0] = L.f.px[i]; out_cent[r*3+1] = L.f.py[i]; out_cent[r*3+2] = L.f.pz[i];
      out_bsel[r] = (float)b;
    }
    return;
  }

  // ============ persistent workers: ball query + stage-1 per centroid (512 thr)
  for (;;) {
    if (tid == 0) {
      int t = atomicAdd(taskctr, 1);
      L.w.task = t;
      if (t < NTASK) {
        int m = t >> 3, b = t & 7;
        while (__hip_atomic_load(progress + b, __ATOMIC_ACQUIRE, __HIP_MEMORY_SCOPE_AGENT) < m + 1)
          __builtin_amdgcn_s_sleep(8);
        int bm = b*MC + m;
        L.w.cxyz[0] = __hip_atomic_load(centf + bm*3 + 0, __ATOMIC_RELAXED, __HIP_MEMORY_SCOPE_AGENT);
        L.w.cxyz[1] = __hip_atomic_load(centf + bm*3 + 1, __ATOMIC_RELAXED, __HIP_MEMORY_SCOPE_AGENT);
        L.w.cxyz[2] = __hip_atomic_load(centf + bm*3 + 2, __ATOMIC_RELAXED, __HIP_MEMORY_SCOPE_AGENT);
      }
      L.w.scnt = 0;
    }
    __syncthreads();
    const int t = L.w.task;
    if (t >= NTASK) return;
    const int m = t >> 3, b = t & 7, bm = b*MC + m;
    const float cx = L.w.cxyz[0], cy = L.w.cxyz[1], cz = L.w.cxyz[2];

    // ---- ball query (exact ref semantics)
    for (int i = tid; i < NPTS; i += 512) {
      size_t o = ((size_t)b*NPTS + i)*3;
      float d = d2ref(cx, cy, cz, pos[o], pos[o+1], pos[o+2]);
      if (d <= 0.04f) {
        int p = atomicAdd(&L.w.scnt, 1);
        if (p < CAP) L.w.keys[p] = ((u64)__float_as_uint(d) << 32) | (u32)i;
      }
    }
    __syncthreads();
    int n = L.w.scnt; if (n > CAP) n = CAP;
    int P = 64; while (P < n) P <<= 1;
    for (int i = n + tid; i < P; i += 512) L.w.keys[i] = ~0ull;
    __syncthreads();
    for (int ks = 2; ks <= P; ks <<= 1)
      for (int js = ks >> 1; js > 0; js >>= 1) {
        for (int i = tid; i < P; i += 512) {
          int l = i ^ js;
          if (l > i) {
            u64 a = L.w.keys[i], c = L.w.keys[l];
            bool up = ((i & ks) == 0);
            if ((a > c) == up) { L.w.keys[i] = c; L.w.keys[l] = a; }
          }
        }
        __syncthreads();
      }
    const int c = n < KNB ? n : KNB;
    if (tid < KNB) L.w.nbrS[tid] = (tid < c) ? (int)(u32)(L.w.keys[tid] & 0xffffffffu) : 0;
    if (tid == 0) { cntpc[bm] = c; atomicAdd(cnt_total, c); }
    __syncthreads();

    // ---- stage-1: H = [x_j, p_j - c_i] (64x67) staged in LDS
    {
      const int ge = tid >> 3, qb = tid & 7;
      const float4* xr = (const float4*)(x + ((size_t)(b*NPTS + L.w.nbrS[ge]))*CINV);
      #pragma unroll
      for (int rep = 0; rep < 2; ++rep) {
        int q = qb + rep*8;
        float4 v = xr[q];
        float* d = L.w.Hs + ge*69 + q*4;
        d[0] = v.x; d[1] = v.y; d[2] = v.z; d[3] = v.w;
      }
    }
    if (tid < 64) {
      int row = b*NPTS + L.w.nbrS[tid];
      L.w.Hs[tid*69+64] = pos[(size_t)row*3+0] - cx;
      L.w.Hs[tid*69+65] = pos[(size_t)row*3+1] - cy;
      L.w.Hs[tid*69+66] = pos[(size_t)row*3+2] - cz;
    }
    __syncthreads();

    // ---- GEMM: thread = (edge, col of 8 ch); W via wave-uniform SCALAR loads
    const int edge = tid & 63;
    const int col  = __builtin_amdgcn_readfirstlane(tid >> 6);  // 0..7
    float acc[8];
    #pragma unroll
    for (int j = 0; j < 8; ++j) acc[j] = 0.f;
    const float* hrow = L.w.Hs + edge*69;
    const float* wcol = W1 + col*8;
    for (int k = 0; k < K1; ++k) {
      float hk = hrow[k];
      const float4* w4 = (const float4*)(wcol + k*CH1);
      float4 a = w4[0], bq = w4[1];
      acc[0] = fmaf(hk, a.x,  acc[0]); acc[1] = fmaf(hk, a.y,  acc[1]);
      acc[2] = fmaf(hk, a.z,  acc[2]); acc[3] = fmaf(hk, a.w,  acc[3]);
      acc[4] = fmaf(hk, bq.x, acc[4]); acc[5] = fmaf(hk, bq.y, acc[5]);
      acc[6] = fmaf(hk, bq.z, acc[6]); acc[7] = fmaf(hk, bq.w, acc[7]);
    }
    const bool valid = edge < c;
    #pragma unroll
    for (int j = 0; j < 8; ++j) acc[j] = valid ? acc[j] : 0.f;
    u32* dst = (u32*)(y1g + ((size_t)bm*64 + edge)*CH1 + col*8);
    #pragma unroll
    for (int j = 0; j < 4; ++j)
      dst[j] = (u32)f2bf(acc[2*j]) | ((u32)f2bf(acc[2*j+1]) << 16);
    // group-16 DPP reductions (pure VALU), 4 partials per value
    #pragma unroll
    for (int j = 0; j < 8; ++j) {
      float s = dppsum16(acc[j]);
      float q = dppsum16(acc[j]*acc[j]);
      if ((edge & 15) == 0) {
        L.w.red[col][j][edge>>4]   = s;
        L.w.red[col][8+j][edge>>4] = q;
      }
    }
    __syncthreads();
    const int slot = bm & (NSLOT-1);
    if (tid < 64) {
      float4 g = *(const float4*)&L.w.red[tid>>3][tid&7][0];
      atomicAdd(&Spart[slot*256 + tid], (g.x+g.y)+(g.z+g.w));
    } else if (tid < 128) {
      int cc = tid - 64;
      float4 g = *(const float4*)&L.w.red[cc>>3][8+(cc&7)][0];
      atomicAdd(&Spart[slot*256 + 128 + cc], (g.x+g.y)+(g.z+g.w));
    }
    // top-of-loop __syncthreads() isolates this task's LDS reads from next task's writes
  }
}

// ---------------------------------------------------------------- W2/W3 -> bf16 MFMA-fragment layout
// For each 16x32 (NxK) tile: lane l, elem j supplies B[k][n]:
// n = Nt*16 + (l&15), k = Kt*32 + (l>>4)*8 + j.  (Layout verified on HW in R11.)
__global__ void k_wconv(const float* __restrict__ W3, const float* __restrict__ W2,
                        u16* __restrict__ W3f, u16* __restrict__ W2f) {
  int blk = blockIdx.x;
  if (blk < 32) {
    int t = blk*256 + threadIdx.x;           // 8192: W3 (N=128 -> 8 Nt, K=64 -> 2 Kt)
    int T = t >> 9, lane = (t >> 3) & 63, j = t & 7;
    int n = (T >> 1)*16 + (lane & 15);
    int k = (T & 1)*32 + (lane >> 4)*8 + j;
    W3f[t] = f2bf(W3[k*CH3 + n]);
  } else {
    int t = (blk - 32)*256 + threadIdx.x;    // 4096: W2 (N=64 -> 4 Nt, K=64 -> 2 Kt)
    int T = t >> 9, lane = (t >> 3) & 63, j = t & 7;
    int n = (T >> 1)*16 + (lane & 15);
    int k = (T & 1)*32 + (lane >> 4)*8 + j;
    W2f[t] = f2bf(W2[k*CH2 + n]);
  }
}

// ---------------------------------------------------------------- stage 2 (MFMA): relu(bn1(y1)) @ W2
// 4 waves; wave wv owns N-tile wv (16 ch). M=64 edges = 4 M-tiles; K=64 = 2 K-tiles.
// C/D layout (verified): col = lane&15, row = (lane>>4)*4 + reg.
__global__ __launch_bounds__(256) void k_s2(const u16* __restrict__ y1g,
                                            const float* __restrict__ SC,
                                            const u16* __restrict__ W2f,
                                            const int* __restrict__ cntpc,
                                            float* __restrict__ Spart,
                                            u16* __restrict__ y2g) {
  __shared__ u16   Hb[64*72];      // bf16 h1, pitch 72
  __shared__ u16   Ob[64*72];      // bf16 y2 staging, pitch 72
  __shared__ float ABs[128];
  __shared__ float redS[4][16][4];
  __shared__ float redQ[4][16][4];
  __shared__ int   cntS;
  const int tid = threadIdx.x, bm = blockIdx.x;
  if (tid == 0) cntS = cntpc[bm];
  if (tid < 128) ABs[tid] = SC[tid];            // A1(64) B1(64)
  __syncthreads();
  {
    const u32* yt = (const u32*)y1g + (size_t)bm*2048;  // 64 edges * 32 u32
    #pragma unroll
    for (int rep = 0; rep < 8; ++rep) {
      int g = rep*256 + tid;
      int e = g >> 5, ch = (g & 31)*2;
      u32 v = yt[g];
      float lo = fmaxf(fmaf(bf2f((u16)(v & 0xffff)), ABs[ch],   ABs[64+ch]),   0.f);
      float hi = fmaxf(fmaf(bf2f((u16)(v >> 16)),    ABs[ch+1], ABs[64+ch+1]), 0.f);
      *(u32*)&Hb[e*72 + ch] = (u32)f2bf(lo) | ((u32)f2bf(hi) << 16);
    }
  }
  __syncthreads();

  const int lane = tid & 63;
  const int wv   = __builtin_amdgcn_readfirstlane(tid >> 6);  // 0..3 == N-tile
  const int r16  = lane & 15, g4 = lane >> 4;
  const int cnt  = cntS;

  // B fragments (global, L2-hot, fragment-ready): tile T = wv*2 + Kt
  bf16x8 bfr[2];
  #pragma unroll
  for (int Kt = 0; Kt < 2; ++Kt)
    bfr[Kt] = *(const bf16x8*)&W2f[((wv*2 + Kt)*64 + lane)*8];

  f32x4 acc[4];
  #pragma unroll
  for (int Mt = 0; Mt < 4; ++Mt) acc[Mt] = (f32x4){0.f, 0.f, 0.f, 0.f};

  #pragma unroll
  for (int Kt = 0; Kt < 2; ++Kt) {
    #pragma unroll
    for (int Mt = 0; Mt < 4; ++Mt) {
      bf16x8 afr = *(const bf16x8*)&Hb[(Mt*16 + r16)*72 + Kt*32 + g4*8];
      acc[Mt] = __builtin_amdgcn_mfma_f32_16x16x32_bf16(afr, bfr[Kt], acc[Mt], 0, 0, 0);
    }
  }

  // epilogue: lane holds channel n = wv*16 + r16; rows Mt*16 + g4*4 + rr in-lane.
  {
    const int n = wv*16 + r16;
    float s = 0.f, q = 0.f;
    #pragma unroll
    for (int Mt = 0; Mt < 4; ++Mt) {
      #pragma unroll
      for (int rr = 0; rr < 4; ++rr) {
        int row = Mt*16 + g4*4 + rr;
        bool valid = row < cnt;
        float av = valid ? acc[Mt][rr] : 0.f;
        s += av; q = fmaf(av, av, q);
        Ob[row*72 + n] = f2bf(av);
      }
    }
    redS[wv][r16][g4] = s;
    redQ[wv][r16][g4] = q;
  }
  __syncthreads();
  // coalesced y2 store + Spart combine
  {
    u32* yt2 = (u32*)y2g + (size_t)bm*2048;
    #pragma unroll
    for (int rep = 0; rep < 8; ++rep) {
      int g = rep*256 + tid;
      int e = g >> 5, c2 = g & 31;
      yt2[g] = *(const u32*)&Ob[e*72 + c2*2];
    }
  }
  const int slot = bm & (NSLOT-1);
  if (tid < 64) {
    float4 g = *(const float4*)&redS[tid>>4][tid&15][0];
    atomicAdd(&Spart[slot*256 + tid], (g.x+g.y)+(g.z+g.w));
  } else if (tid < 128) {
    int c = tid - 64;
    float4 g = *(const float4*)&redQ[c>>4][c&15][0];
    atomicAdd(&Spart[slot*256 + 128 + c], (g.x+g.y)+(g.z+g.w));
  }
}

// ---------------------------------------------------------------- stage 3 (MFMA): relu(bn2(y2)) @ W3
// wave wv owns 32 output channels (2 N-tiles of 16); M=64 edges = 4 M-tiles; K=64 = 2 K-tiles.
__global__ __launch_bounds__(256) void k_s3(const u16* __restrict__ y2g,
                                            const float* __restrict__ SC,
                                            const u16* __restrict__ W3f,
                                            const int* __restrict__ cntpc,
                                            float* __restrict__ Spart,
                                            float* __restrict__ mxmn) {
  __shared__ u16   Hb[64*72];      // bf16 h2, pitch 72
  __shared__ float ABs[128];
  __shared__ float redS[4][32][4];
  __shared__ float redQ[4][32][4];
  __shared__ float redM[4][32][4];
  __shared__ float redN[4][32][4];
  __shared__ int   cntS;
  const int tid = threadIdx.x, bm = blockIdx.x;
  if (tid == 0) cntS = cntpc[bm];
  if (tid < 128) ABs[tid] = SC[128 + tid];      // A2(64) B2(64)
  __syncthreads();
  {
    const u32* yt = (const u32*)y2g + (size_t)bm*2048;
    #pragma unroll
    for (int rep = 0; rep < 8; ++rep) {
      int g = rep*256 + tid;
      int e = g >> 5, ch = (g & 31)*2;
      u32 v = yt[g];
      float lo = fmaxf(fmaf(bf2f((u16)(v & 0xffff)), ABs[ch],   ABs[64+ch]),   0.f);
      float hi = fmaxf(fmaf(bf2f((u16)(v >> 16)),    ABs[ch+1], ABs[64+ch+1]), 0.f);
      *(u32*)&Hb[e*72 + ch] = (u32)f2bf(lo) | ((u32)f2bf(hi) << 16);
    }
  }
  __syncthreads();

  const int lane = tid & 63;
  const int wv   = __builtin_amdgcn_readfirstlane(tid >> 6);  // 0..3
  const int r16  = lane & 15, g4 = lane >> 4;
  const int cnt  = cntS;

  // B fragments (global, L2-hot, fragment-ready)
  bf16x8 bfr[2][2];
  #pragma unroll
  for (int Nt = 0; Nt < 2; ++Nt)
    #pragma unroll
    for (int Kt = 0; Kt < 2; ++Kt)
      bfr[Nt][Kt] = *(const bf16x8*)&W3f[(((wv*2 + Nt)*2 + Kt)*64 + lane)*8];

  f32x4 acc[4][2];
  #pragma unroll
  for (int Mt = 0; Mt < 4; ++Mt)
    #pragma unroll
    for (int Nt = 0; Nt < 2; ++Nt)
      acc[Mt][Nt] = (f32x4){0.f, 0.f, 0.f, 0.f};

  #pragma unroll
  for (int Kt = 0; Kt < 2; ++Kt) {
    #pragma unroll
    for (int Mt = 0; Mt < 4; ++Mt) {
      bf16x8 afr = *(const bf16x8*)&Hb[(Mt*16 + r16)*72 + Kt*32 + g4*8];
      #pragma unroll
      for (int Nt = 0; Nt < 2; ++Nt)
        acc[Mt][Nt] = __builtin_amdgcn_mfma_f32_16x16x32_bf16(afr, bfr[Nt][Kt],
                                                              acc[Mt][Nt], 0, 0, 0);
    }
  }

  // epilogue: lane holds channel n = wv*32 + Nt*16 + r16; rows Mt*16 + g4*4 + rr in-lane.
  #pragma unroll
  for (int Nt = 0; Nt < 2; ++Nt) {
    float s = 0.f, q = 0.f, mx = -1e30f, mn = 1e30f;
    #pragma unroll
    for (int Mt = 0; Mt < 4; ++Mt) {
      #pragma unroll
      for (int rr = 0; rr < 4; ++rr) {
        int row = Mt*16 + g4*4 + rr;
        float v = acc[Mt][Nt][rr];
        bool valid = row < cnt;
        float av = valid ? v : 0.f;
        s += av; q = fmaf(av, av, q);
        mx = fmaxf(mx, valid ? v : -1e30f);
        mn = fminf(mn, valid ? v :  1e30f);
      }
    }
    redS[wv][Nt*16 + r16][g4] = s;
    redQ[wv][Nt*16 + r16][g4] = q;
    redM[wv][Nt*16 + r16][g4] = mx;
    redN[wv][Nt*16 + r16][g4] = mn;
  }
  __syncthreads();
  const int slot = bm & (NSLOT-1);
  if (tid < 128) {
    float4 g = *(const float4*)&redS[tid>>5][tid&31][0];
    atomicAdd(&Spart[slot*256 + tid], (g.x+g.y)+(g.z+g.w));
    float4 gm = *(const float4*)&redM[tid>>5][tid&31][0];
    mxmn[(size_t)bm*256 + tid] = fmaxf(fmaxf(gm.x, gm.y), fmaxf(gm.z, gm.w));
  } else {
    int c = tid - 128;
    float4 g = *(const float4*)&redQ[c>>5][c&31][0];
    atomicAdd(&Spart[slot*256 + 128 + c], (g.x+g.y)+(g.z+g.w));
    float4 gm = *(const float4*)&redN[c>>5][c&31][0];
    mxmn[(size_t)bm*256 + 128 + c] = fminf(fminf(gm.x, gm.y), fminf(gm.z, gm.w));
  }
}

// ---------------------------------------------------------------- stage 4: bn3+relu+maxpool from per-block max/min
// max_e relu(a*y+b) = relu(a*max_e(y)+b) for a>0 (monotone correctly-rounded ops
// commute with max); use min_e(y) for a<0. Exact vs the elementwise scan.
__global__ __launch_bounds__(128) void k_s4(const float* __restrict__ mxmn,
                                            const float* __restrict__ SC,
                                            float* __restrict__ out0) {
  const int tid = threadIdx.x, bm = blockIdx.x;
  const float a = SC[256 + tid], b = SC[384 + tid];
  const float mx = mxmn[(size_t)bm*256 + tid];
  const float mn = mxmn[(size_t)bm*256 + 128 + tid];
  const float v = (a > 0.f) ? mx : mn;
  out0[(size_t)bm*CH3 + tid] = fmaxf(fmaf(v, a, b), 0.f);
}

// ---------------------------------------------------------------- finalize
__global__ void k_finalize(const float* __restrict__ Spart,
                           const float* __restrict__ g, const float* __restrict__ bb,
                           const int* __restrict__ cnt_total,
                           float* __restrict__ Aout, float* __restrict__ Bout, int C) {
  int c = threadIdx.x;
  if (c < C) {
    float s = 0.f, q = 0.f;
    for (int sl = 0; sl < NSLOT; ++sl) {
      s += Spart[sl*256 + c];
      q += Spart[sl*256 + 128 + c];
    }
    float n = (float)(*cnt_total); if (n < 1.f) n = 1.f;
    float mu  = s / n;
    float var = q / n - mu*mu; if (var < 0.f) var = 0.f;
    float inv = 1.0f / sqrtf(var + 1e-5f);
    float a = g[c] * inv;
    Aout[c] = a;
    Bout[c] = bb[c] - mu*a;
  }
}

// ---------------------------------------------------------------- host
extern "C" void kernel_launch(void* const* d_in, const int* in_sizes, int n_in,
                              void* d_out, int out_size, void* d_ws, size_t ws_size,
                              hipStream_t stream) {
  (void)in_sizes; (void)n_in; (void)out_size; (void)ws_size;
  const float* x   = (const float*)d_in[0];
  const float* pos = (const float*)d_in[1];
  const float* W1  = (const float*)d_in[3];
  const float* g1  = (const float*)d_in[4];
  const float* b1  = (const float*)d_in[5];
  const float* W2  = (const float*)d_in[6];
  const float* g2  = (const float*)d_in[7];
  const float* b2  = (const float*)d_in[8];
  const float* W3  = (const float*)d_in[9];
  const float* g3  = (const float*)d_in[10];
  const float* b3  = (const float*)d_in[11];

  float* out0     = (float*)d_out;
  float* out_cent = out0 + (size_t)NB*MC*CH3;
  float* out_bsel = out_cent + (size_t)NB*MC*3;

  char* base = (char*)d_ws;
  size_t off = 0;
  auto carve = [&](size_t bytes) -> char* {
    char* p = base + off;
    off = (off + bytes + 255) & ~(size_t)255;
    return p;
  };
  float* centf = (float*)carve(sizeof(float)*NB*MC*3);
  int*   cntpc = (int*)  carve(sizeof(int)*NB*MC);
  char*  zeroblk = carve(256 + 3*NSLOT*256*sizeof(float));
  int*   cnt_total = (int*)zeroblk;
  int*   taskctr   = cnt_total + 1;
  int*   progress  = cnt_total + 2;    // 8 ints
  float* Sp1 = (float*)(zeroblk + 256);
  float* Sp2 = Sp1 + NSLOT*256;
  float* Sp3 = Sp2 + NSLOT*256;
  float* SC = (float*)carve(512*sizeof(float));  // A1 B1 A2 B2 A3(128) B3(128)
  u16* y1g = (u16*)carve((size_t)NE*CH1*2);
  u16* y2g = (u16*)carve((size_t)NE*CH2*2);
  float* mxmn = (float*)carve((size_t)NB*MC*256*sizeof(float));  // 8 MB
  u16* W3f = (u16*)carve(16*64*8*sizeof(u16));   // 16 KB fragment-ready W3 (bf16)
  u16* W2f = (u16*)carve(8*64*8*sizeof(u16));    //  8 KB fragment-ready W2 (bf16)

  hipMemsetAsync(zeroblk, 0, 256 + 3*NSLOT*256*sizeof(float), stream);
  k_wconv<<<48, 256, 0, stream>>>(W3, W2, W3f, W2f);
  k_front<<<NBLK, 512, 0, stream>>>(x, pos, centf, out_cent, out_bsel,
                                    W1, Sp1, y1g, cntpc, cnt_total, progress, taskctr);
  k_finalize<<<1, 128, 0, stream>>>(Sp1, g1, b1, cnt_total, SC + 0,   SC + 64,  CH1);
  dim3 sg(NB*MC), sb(256);
  k_s2<<<sg, sb, 0, stream>>>(y1g, SC, W2f, cntpc, Sp2, y2g);
  k_finalize<<<1, 128, 0, stream>>>(Sp2, g2, b2, cnt_total, SC + 128, SC + 192, CH2);
  k_s3<<<sg, sb, 0, stream>>>(y2g, SC, W3f, cntpc, Sp3, mxmn);
  k_finalize<<<1, 128, 0, stream>>>(Sp3, g3, b3, cnt_total, SC + 256, SC + 384, CH3);
  k_s4<<<sg, 128, 0, stream>>>(mxmn, SC, out0);
}